// Round 11
// baseline (850.389 us; speedup 1.0000x reference)
//
#include <hip/hip_runtime.h>
#include <hip/hip_bf16.h>

typedef __attribute__((ext_vector_type(8))) short short8;
typedef __attribute__((ext_vector_type(4))) float f32x4;
typedef __attribute__((ext_vector_type(8))) unsigned short u16x8;
typedef __attribute__((ext_vector_type(4))) unsigned short u16x4;

// ---------- helpers ----------
__device__ __forceinline__ unsigned short f2bf(float f) {
  unsigned u = __float_as_uint(f);
  u += 0x7fffu + ((u >> 16) & 1u);          // round-to-nearest-even
  return (unsigned short)(u >> 16);
}
__device__ __forceinline__ float silu_f(float x) { return x / (1.f + __expf(-x)); }
__device__ __forceinline__ float red16(float v) {
  v += __shfl_xor(v, 1); v += __shfl_xor(v, 2);
  v += __shfl_xor(v, 4); v += __shfl_xor(v, 8);
  return v;
}
template <int CTRL>
__device__ __forceinline__ float dpp_mv(float v) {
  return __int_as_float(__builtin_amdgcn_update_dpp(0, __float_as_int(v), CTRL, 0xF, 0xF, true));
}
__device__ __forceinline__ float red16d(float v) {
  v += dpp_mv<0xB1>(v);   // quad_perm [1,0,3,2]
  v += dpp_mv<0x4E>(v);   // quad_perm [2,3,0,1]
  v += dpp_mv<0x141>(v);  // row_half_mirror
  v += dpp_mv<0x140>(v);  // row_mirror
  return v;
}
__device__ __forceinline__ float red32(float v) {  // sum within each 32-lane group
  v = red16d(v);
  v += __shfl_xor(v, 16);
  return v;
}
__device__ __forceinline__ void gload16(const void* g, void* l) {
  __builtin_amdgcn_global_load_lds((const __attribute__((address_space(1))) void*)g,
                                   (__attribute__((address_space(3))) void*)l, 16, 0, 0);
}

// ---------- ALL weight transposes in ONE launch (desc table) ----------
struct TDesc { const float* src; unsigned short* dst; int R, C, tilesX, start; };
struct TDescs { TDesc d[11]; };

__global__ void __launch_bounds__(256) trans_all_kernel(TDescs ds) {
  __shared__ float tile[64][65];   // tile[col'][row']
  const int bid = blockIdx.x;
  int e = 0;
#pragma unroll
  for (int i = 1; i < 11; i++) e = (bid >= ds.d[i].start) ? i : e;
  const float* __restrict__ src = ds.d[e].src;
  unsigned short* __restrict__ dst = ds.d[e].dst;
  const int R = ds.d[e].R, C = ds.d[e].C;
  const int local = bid - ds.d[e].start;
  const int c0 = (local % ds.d[e].tilesX) * 64;
  const int r0 = (local / ds.d[e].tilesX) * 64;
  const int tid = threadIdx.x;
  const int l = tid & 15, g = tid >> 4;
#pragma unroll
  for (int i = 0; i < 4; i++) {
    const int r = r0 + g + 16 * i;
    const int c = c0 + 4 * l;
    if (r < R) {
      if (c + 3 < C) {
        float4 v = *(const float4*)(src + (size_t)r * C + c);
        tile[4 * l + 0][g + 16 * i] = v.x;
        tile[4 * l + 1][g + 16 * i] = v.y;
        tile[4 * l + 2][g + 16 * i] = v.z;
        tile[4 * l + 3][g + 16 * i] = v.w;
      } else {
#pragma unroll
        for (int j = 0; j < 4; j++)
          if (c + j < C) tile[4 * l + j][g + 16 * i] = src[(size_t)r * C + c + j];
      }
    }
  }
  __syncthreads();
#pragma unroll
  for (int i = 0; i < 4; i++) {
    const int cc = c0 + g + 16 * i;
    const int rc = r0 + 4 * l;
    if (cc < C) {
      if (rc + 3 < R) {
        u16x4 o;
        o[0] = f2bf(tile[g + 16 * i][4 * l + 0]);
        o[1] = f2bf(tile[g + 16 * i][4 * l + 1]);
        o[2] = f2bf(tile[g + 16 * i][4 * l + 2]);
        o[3] = f2bf(tile[g + 16 * i][4 * l + 3]);
        *(u16x4*)(dst + (size_t)cc * R + rc) = o;
      } else {
#pragma unroll
        for (int j = 0; j < 4; j++)
          if (rc + j < R) dst[(size_t)cc * R + rc + j] = f2bf(tile[g + 16 * i][4 * l + j]);
      }
    }
  }
}

// ---------- rmsnorm (D=2048) -> bf16 ----------
__global__ void __launch_bounds__(256) rmsnorm_bf16_kernel(const float* __restrict__ x,
                                                           const float* __restrict__ w,
                                                           unsigned short* __restrict__ outb) {
  const int t = blockIdx.x, tid = threadIdx.x;
  const float* xr = x + (size_t)t * 2048 + tid * 8;
  float4 v0 = *(const float4*)xr, v1 = *(const float4*)(xr + 4);
  float ss = v0.x*v0.x + v0.y*v0.y + v0.z*v0.z + v0.w*v0.w
           + v1.x*v1.x + v1.y*v1.y + v1.z*v1.z + v1.w*v1.w;
#pragma unroll
  for (int m = 1; m < 64; m <<= 1) ss += __shfl_xor(ss, m);
  __shared__ float sb[4];
  if ((tid & 63) == 0) sb[tid >> 6] = ss;
  __syncthreads();
  float rn = rsqrtf((sb[0] + sb[1] + sb[2] + sb[3]) * (1.f / 2048.f) + 1e-6f);
  const float* wr = w + tid * 8;
  float4 w0 = *(const float4*)wr, w1 = *(const float4*)(wr + 4);
  u16x8 r;
  r[0]=f2bf(v0.x*rn*w0.x); r[1]=f2bf(v0.y*rn*w0.y); r[2]=f2bf(v0.z*rn*w0.z); r[3]=f2bf(v0.w*rn*w0.w);
  r[4]=f2bf(v1.x*rn*w1.x); r[5]=f2bf(v1.y*rn*w1.y); r[6]=f2bf(v1.z*rn*w1.z); r[7]=f2bf(v1.w*rn*w1.w);
  *(u16x8*)(outb + (size_t)t * 2048 + tid * 8) = r;
}

// ---------- x1 = x + y1 + y2 ; h2b = bf16(rmsnorm(x1)*w) ----------
__global__ void __launch_bounds__(256) add3_rmsnorm_kernel(const float* __restrict__ x,
                                                           const float* __restrict__ y1,
                                                           const float* __restrict__ y2,
                                                           const float* __restrict__ w,
                                                           float* __restrict__ x1,
                                                           unsigned short* __restrict__ h2b) {
  const int t = blockIdx.x, tid = threadIdx.x;
  const int c = tid * 8;
  const float* xr = x + (size_t)t * 2048 + c;
  const float* yr = y1 + (size_t)t * 2048 + c;
  const float* zr = y2 + (size_t)t * 2048 + c;
  float s[8]; float ss = 0.f;
  float4 a0 = *(const float4*)xr, a1 = *(const float4*)(xr + 4);
  float4 b0 = *(const float4*)yr, b1 = *(const float4*)(yr + 4);
  float4 c0 = *(const float4*)zr, c1 = *(const float4*)(zr + 4);
  s[0]=a0.x+b0.x+c0.x; s[1]=a0.y+b0.y+c0.y; s[2]=a0.z+b0.z+c0.z; s[3]=a0.w+b0.w+c0.w;
  s[4]=a1.x+b1.x+c1.x; s[5]=a1.y+b1.y+c1.y; s[6]=a1.z+b1.z+c1.z; s[7]=a1.w+b1.w+c1.w;
#pragma unroll
  for (int j = 0; j < 8; j++) ss += s[j] * s[j];
#pragma unroll
  for (int m = 1; m < 64; m <<= 1) ss += __shfl_xor(ss, m);
  __shared__ float sb[4];
  if ((tid & 63) == 0) sb[tid >> 6] = ss;
  __syncthreads();
  float rn = rsqrtf((sb[0] + sb[1] + sb[2] + sb[3]) * (1.f / 2048.f) + 1e-6f);
  float* xo = x1 + (size_t)t * 2048 + c;
  *(float4*)xo = *(float4*)&s[0];
  *(float4*)(xo + 4) = *(float4*)&s[4];
  const float* wr = w + c;
  float4 w0 = *(const float4*)wr, w1 = *(const float4*)(wr + 4);
  float wv[8] = {w0.x,w0.y,w0.z,w0.w,w1.x,w1.y,w1.z,w1.w};
  u16x8 r;
#pragma unroll
  for (int j = 0; j < 8; j++) r[j] = f2bf(s[j] * rn * wv[j]);
  *(u16x8*)(h2b + (size_t)t * 2048 + c) = r;
}

// ---------- bf16 GEMM: C[M,N] = A[M,K] * Bt[N,K]^T  (m97-style, strided) ----------
__global__ void __launch_bounds__(256) gemm_bt_kernel(const unsigned short* __restrict__ A,
                                                      const unsigned short* __restrict__ Bt,
                                                      float* __restrict__ C,
                                                      int M, int N, int K, int lda, int ldb) {
  __shared__ unsigned short As[128][32];
  __shared__ unsigned short Bs[128][32];
  const int tid = threadIdx.x;
  const int m0 = blockIdx.x << 7, n0 = blockIdx.y << 7;
  const int wave = tid >> 6, lane = tid & 63;
  const int wm = (wave >> 1) << 6, wn = (wave & 1) << 6;
  const int lrow = lane >> 2, lcol = lane & 3;
  const int ar0 = wave * 16 + lrow;
  const int ar1 = ar0 + 64;
  int br0 = n0 + ar0; br0 = br0 < N ? br0 : N - 1;
  int br1 = n0 + ar1; br1 = br1 < N ? br1 : N - 1;
  const unsigned short* Aptr0 = A + (size_t)(m0 + ar0) * lda + ((lcol ^ (ar0 & 3)) << 3);
  const unsigned short* Aptr1 = A + (size_t)(m0 + ar1) * lda + ((lcol ^ (ar1 & 3)) << 3);
  const unsigned short* Bptr0 = Bt + (size_t)br0 * ldb + ((lcol ^ (ar0 & 3)) << 3);
  const unsigned short* Bptr1 = Bt + (size_t)br1 * ldb + ((lcol ^ (ar1 & 3)) << 3);
  unsigned short* lA0 = &As[wave * 16][0];
  unsigned short* lA1 = &As[64 + wave * 16][0];
  unsigned short* lB0 = &Bs[wave * 16][0];
  unsigned short* lB1 = &Bs[64 + wave * 16][0];
  const int frow = lane & 15, fkb = lane >> 4;
  f32x4 acc[4][4];
#pragma unroll
  for (int i = 0; i < 4; i++)
#pragma unroll
    for (int j = 0; j < 4; j++) acc[i][j] = (f32x4){0.f, 0.f, 0.f, 0.f};

  for (int k0 = 0; k0 < K; k0 += 32) {
    gload16(Aptr0 + k0, lA0);
    gload16(Aptr1 + k0, lA1);
    gload16(Bptr0 + k0, lB0);
    gload16(Bptr1 + k0, lB1);
    __syncthreads();
    short8 af[4], bfr[4];
#pragma unroll
    for (int i = 0; i < 4; i++) {
      int ra = wm + i * 16 + frow;
      af[i] = *(const short8*)&As[ra][(fkb ^ (ra & 3)) << 3];
      int rb = wn + i * 16 + frow;
      bfr[i] = *(const short8*)&Bs[rb][(fkb ^ (rb & 3)) << 3];
    }
#pragma unroll
    for (int i = 0; i < 4; i++)
#pragma unroll
      for (int j = 0; j < 4; j++)
        acc[i][j] = __builtin_amdgcn_mfma_f32_16x16x32_bf16(af[i], bfr[j], acc[i][j], 0, 0, 0);
    __syncthreads();
  }
  const int crow = (lane >> 4) << 2, ccol = lane & 15;
#pragma unroll
  for (int i = 0; i < 4; i++) {
    const int gr = m0 + wm + i * 16 + crow;
#pragma unroll
    for (int j = 0; j < 4; j++) {
      const int gc = n0 + wn + j * 16 + ccol;
      if (gc < N) {
#pragma unroll
        for (int r = 0; r < 4; r++) C[(size_t)(gr + r) * N + gc] = acc[i][j][r];
      }
    }
  }
}

// ---------- split-K x2 GEMM in ONE launch: blockIdx.z picks K-half ----------
__global__ void __launch_bounds__(256) gemm_bt_splitk2_kernel(const unsigned short* __restrict__ Abase,
                                                              const unsigned short* __restrict__ Btbase,
                                                              float* __restrict__ C0,
                                                              float* __restrict__ C1,
                                                              int M, int N, int Khalf,
                                                              int lda, int ldb) {
  const unsigned short* A = Abase + (size_t)blockIdx.z * Khalf;
  const unsigned short* Bt = Btbase + (size_t)blockIdx.z * Khalf;
  float* C = blockIdx.z ? C1 : C0;
  __shared__ unsigned short As[128][32];
  __shared__ unsigned short Bs[128][32];
  const int tid = threadIdx.x;
  const int m0 = blockIdx.x << 7, n0 = blockIdx.y << 7;
  const int wave = tid >> 6, lane = tid & 63;
  const int wm = (wave >> 1) << 6, wn = (wave & 1) << 6;
  const int lrow = lane >> 2, lcol = lane & 3;
  const int ar0 = wave * 16 + lrow;
  const int ar1 = ar0 + 64;
  int br0 = n0 + ar0; br0 = br0 < N ? br0 : N - 1;
  int br1 = n0 + ar1; br1 = br1 < N ? br1 : N - 1;
  const unsigned short* Aptr0 = A + (size_t)(m0 + ar0) * lda + ((lcol ^ (ar0 & 3)) << 3);
  const unsigned short* Aptr1 = A + (size_t)(m0 + ar1) * lda + ((lcol ^ (ar1 & 3)) << 3);
  const unsigned short* Bptr0 = Bt + (size_t)br0 * ldb + ((lcol ^ (ar0 & 3)) << 3);
  const unsigned short* Bptr1 = Bt + (size_t)br1 * ldb + ((lcol ^ (ar1 & 3)) << 3);
  unsigned short* lA0 = &As[wave * 16][0];
  unsigned short* lA1 = &As[64 + wave * 16][0];
  unsigned short* lB0 = &Bs[wave * 16][0];
  unsigned short* lB1 = &Bs[64 + wave * 16][0];
  const int frow = lane & 15, fkb = lane >> 4;
  f32x4 acc[4][4];
#pragma unroll
  for (int i = 0; i < 4; i++)
#pragma unroll
    for (int j = 0; j < 4; j++) acc[i][j] = (f32x4){0.f, 0.f, 0.f, 0.f};

  for (int k0 = 0; k0 < Khalf; k0 += 32) {
    gload16(Aptr0 + k0, lA0);
    gload16(Aptr1 + k0, lA1);
    gload16(Bptr0 + k0, lB0);
    gload16(Bptr1 + k0, lB1);
    __syncthreads();
    short8 af[4], bfr[4];
#pragma unroll
    for (int i = 0; i < 4; i++) {
      int ra = wm + i * 16 + frow;
      af[i] = *(const short8*)&As[ra][(fkb ^ (ra & 3)) << 3];
      int rb = wn + i * 16 + frow;
      bfr[i] = *(const short8*)&Bs[rb][(fkb ^ (rb & 3)) << 3];
    }
#pragma unroll
    for (int i = 0; i < 4; i++)
#pragma unroll
      for (int j = 0; j < 4; j++)
        acc[i][j] = __builtin_amdgcn_mfma_f32_16x16x32_bf16(af[i], bfr[j], acc[i][j], 0, 0, 0);
    __syncthreads();
  }
  const int crow = (lane >> 4) << 2, ccol = lane & 15;
#pragma unroll
  for (int i = 0; i < 4; i++) {
    const int gr = m0 + wm + i * 16 + crow;
#pragma unroll
    for (int j = 0; j < 4; j++) {
      const int gc = n0 + wn + j * 16 + ccol;
      if (gc < N) {
#pragma unroll
        for (int r = 0; r < 4; r++) C[(size_t)(gr + r) * N + gc] = acc[i][j][r];
      }
    }
  }
}

// ---------- fused MLP1: mid = bf16(silu(A*B1t^T) * (A*B2t^T)), N=8192, K=2048 ----------
__global__ void __launch_bounds__(256) gemm_dual_swiglu_kernel(const unsigned short* __restrict__ A,
                                                               const unsigned short* __restrict__ Bt,
                                                               unsigned short* __restrict__ mid) {
  __shared__ unsigned short As[128][32];
  __shared__ unsigned short B1s[128][32];
  __shared__ unsigned short B2s[128][32];
  const int tid = threadIdx.x;
  const int m0 = blockIdx.x << 7, n0 = blockIdx.y << 7;
  const int wave = tid >> 6, lane = tid & 63;
  const int wm = (wave >> 1) << 6, wn = (wave & 1) << 6;
  const int lrow = lane >> 2, lcol = lane & 3;
  const int ar0 = wave * 16 + lrow;
  const int ar1 = ar0 + 64;
  const unsigned short* Aptr0 = A + (size_t)(m0 + ar0) * 2048 + ((lcol ^ (ar0 & 3)) << 3);
  const unsigned short* Aptr1 = A + (size_t)(m0 + ar1) * 2048 + ((lcol ^ (ar1 & 3)) << 3);
  const unsigned short* B1p0 = Bt + (size_t)(n0 + ar0) * 2048 + ((lcol ^ (ar0 & 3)) << 3);
  const unsigned short* B1p1 = Bt + (size_t)(n0 + ar1) * 2048 + ((lcol ^ (ar1 & 3)) << 3);
  const unsigned short* B2p0 = B1p0 + (size_t)8192 * 2048;
  const unsigned short* B2p1 = B1p1 + (size_t)8192 * 2048;
  unsigned short* lA0 = &As[wave * 16][0];
  unsigned short* lA1 = &As[64 + wave * 16][0];
  unsigned short* lB10 = &B1s[wave * 16][0];
  unsigned short* lB11 = &B1s[64 + wave * 16][0];
  unsigned short* lB20 = &B2s[wave * 16][0];
  unsigned short* lB21 = &B2s[64 + wave * 16][0];
  const int frow = lane & 15, fkb = lane >> 4;
  f32x4 acc1[4][4], acc2[4][4];
#pragma unroll
  for (int i = 0; i < 4; i++)
#pragma unroll
    for (int j = 0; j < 4; j++) {
      acc1[i][j] = (f32x4){0.f, 0.f, 0.f, 0.f};
      acc2[i][j] = (f32x4){0.f, 0.f, 0.f, 0.f};
    }
  for (int k0 = 0; k0 < 2048; k0 += 32) {
    gload16(Aptr0 + k0, lA0);
    gload16(Aptr1 + k0, lA1);
    gload16(B1p0 + k0, lB10);
    gload16(B1p1 + k0, lB11);
    gload16(B2p0 + k0, lB20);
    gload16(B2p1 + k0, lB21);
    __syncthreads();
    short8 af[4], b1f[4], b2f[4];
#pragma unroll
    for (int i = 0; i < 4; i++) {
      int ra = wm + i * 16 + frow;
      af[i] = *(const short8*)&As[ra][(fkb ^ (ra & 3)) << 3];
      int rb = wn + i * 16 + frow;
      b1f[i] = *(const short8*)&B1s[rb][(fkb ^ (rb & 3)) << 3];
      b2f[i] = *(const short8*)&B2s[rb][(fkb ^ (rb & 3)) << 3];
    }
#pragma unroll
    for (int i = 0; i < 4; i++)
#pragma unroll
      for (int j = 0; j < 4; j++) {
        acc1[i][j] = __builtin_amdgcn_mfma_f32_16x16x32_bf16(af[i], b1f[j], acc1[i][j], 0, 0, 0);
        acc2[i][j] = __builtin_amdgcn_mfma_f32_16x16x32_bf16(af[i], b2f[j], acc2[i][j], 0, 0, 0);
      }
    __syncthreads();
  }
  const int crow = (lane >> 4) << 2, ccol = lane & 15;
#pragma unroll
  for (int i = 0; i < 4; i++) {
    const int gr = m0 + wm + i * 16 + crow;
#pragma unroll
    for (int j = 0; j < 4; j++) {
      const int gc = n0 + wn + j * 16 + ccol;
#pragma unroll
      for (int r = 0; r < 4; r++)
        mid[(size_t)(gr + r) * 8192 + gc] = f2bf(silu_f(acc1[i][j][r]) * acc2[i][j][r]);
    }
  }
}

// ---------- MERGED: causal dwconv + silu + l2norm + qk dot + gates ----------
// phase 1 (256 thr): conv for row t, qk per head -> LDS; phase 2 (128 thr):
// decay gate (8-thread dot per head), beta, g4 pack, gab bf16.
__global__ void __launch_bounds__(256) conv_gates_kernel(const float* __restrict__ proj,
                                                         const float* __restrict__ cq,
                                                         const float* __restrict__ ck,
                                                         const float* __restrict__ cv,
                                                         const float* __restrict__ small,
                                                         const float* __restrict__ wfb,
                                                         const float* __restrict__ a_log,
                                                         const float* __restrict__ dtb,
                                                         float* __restrict__ q, float* __restrict__ k,
                                                         float* __restrict__ v,
                                                         float4* __restrict__ g4,
                                                         unsigned short* __restrict__ gab) {
  __shared__ float qksh[16];
  const int t = blockIdx.x, tid = threadIdx.x;
  const int c = tid << 3;
  float aq[8] = {0,0,0,0,0,0,0,0}, ak[8] = {0,0,0,0,0,0,0,0}, av[8] = {0,0,0,0,0,0,0,0};
#pragma unroll
  for (int i = 0; i < 4; i++) {
    const int tt = t + i - 3;
    if (tt < 0) continue;
    const float* pr = proj + (size_t)tt * 6144;
    float pq[8], pk[8], pv[8], w0[8], w1[8], w2[8];
    *(float4*)&pq[0] = *(const float4*)(pr + c);        *(float4*)&pq[4] = *(const float4*)(pr + c + 4);
    *(float4*)&pk[0] = *(const float4*)(pr + 2048 + c); *(float4*)&pk[4] = *(const float4*)(pr + 2048 + c + 4);
    *(float4*)&pv[0] = *(const float4*)(pr + 4096 + c); *(float4*)&pv[4] = *(const float4*)(pr + 4096 + c + 4);
    *(float4*)&w0[0] = *(const float4*)(cq + i * 2048 + c); *(float4*)&w0[4] = *(const float4*)(cq + i * 2048 + c + 4);
    *(float4*)&w1[0] = *(const float4*)(ck + i * 2048 + c); *(float4*)&w1[4] = *(const float4*)(ck + i * 2048 + c + 4);
    *(float4*)&w2[0] = *(const float4*)(cv + i * 2048 + c); *(float4*)&w2[4] = *(const float4*)(cv + i * 2048 + c + 4);
#pragma unroll
    for (int j = 0; j < 8; j++) { aq[j] += w0[j]*pq[j]; ak[j] += w1[j]*pk[j]; av[j] += w2[j]*pv[j]; }
  }
  float sq[8], sk[8], sv[8]; float ssq = 0.f, ssk = 0.f;
#pragma unroll
  for (int j = 0; j < 8; j++) {
    sq[j] = silu_f(aq[j]); ssq += sq[j]*sq[j];
    sk[j] = silu_f(ak[j]); ssk += sk[j]*sk[j];
    sv[j] = silu_f(av[j]);
  }
  ssq = red16(ssq); ssk = red16(ssk);
  const float rq = rsqrtf(ssq + 1e-6f) * 0.08838834764831845f;  // * DK^-0.5
  const float rk = rsqrtf(ssk + 1e-6f);
  float oq[8], ok[8]; float qkl = 0.f;
#pragma unroll
  for (int j = 0; j < 8; j++) { oq[j] = sq[j]*rq; ok[j] = sk[j]*rk; qkl += oq[j]*ok[j]; }
  qkl = red16(qkl);
  if ((tid & 15) == 0) qksh[tid >> 4] = qkl;
  float* qo = q + (size_t)t * 2048 + c;
  *(float4*)qo = *(float4*)&oq[0]; *(float4*)(qo + 4) = *(float4*)&oq[4];
  float* ko = k + (size_t)t * 2048 + c;
  *(float4*)ko = *(float4*)&ok[0]; *(float4*)(ko + 4) = *(float4*)&ok[4];
  float* vo = v + (size_t)t * 2048 + c;
  *(float4*)vo = *(float4*)&sv[0]; *(float4*)(vo + 4) = *(float4*)&sv[4];
  __syncthreads();
  if (tid < 128) {
    const float* srow = small + (size_t)t * 272;
    const int hh = tid >> 3, j = tid & 7;
    float d = 0.f;
#pragma unroll
    for (int i = 0; i < 16; i++) d += srow[j * 16 + i] * wfb[(j * 16 + i) * 16 + hh];
    d += __shfl_xor(d, 1); d += __shfl_xor(d, 2); d += __shfl_xor(d, 4);
    if (j == 0) {
      d += dtb[hh];
      float sp = (d > 20.f) ? d : log1pf(expf(d));
      float eg = expf(-expf(a_log[hh]) * sp);
      float bt = 1.f / (1.f + expf(-srow[128 + hh]));
      g4[t * 16 + hh] = make_float4(eg, bt, qksh[hh], 0.f);
    }
    gab[(size_t)t * 128 + tid] = f2bf(srow[144 + tid]);
  }
}

// ---------- gated delta-rule scan v7: 32-lane k-groups, 12-reg slots ----------
// one wave = 2 v-cols of one head; k spread over 32 lanes (float4 each).
// Slot = 12 VGPRs -> 8 slots = 96 regs: better odds the allocator keeps the
// 8-deep prefetch live (r3's 20-reg slots were demoted, VGPR=104).
struct Slot2 { float4 k0, q0; float eg, qk, btv, bteg; };

__device__ __forceinline__ void load_slot2(Slot2& X, const float* kb, const float* qb,
                                           const float* vb, const float4* g4b, int tt) {
  X.k0 = *(const float4*)(kb + (size_t)tt * 2048);
  X.q0 = *(const float4*)(qb + (size_t)tt * 2048);
  float4 g = g4b[(size_t)tt * 16];
  float v = vb[(size_t)tt * 2048];
  X.eg = g.x; X.qk = g.z;
  X.btv = g.y * v;            // off-chain precompute
  X.bteg = g.y * g.x;
}

__device__ __forceinline__ void step_slot2(const Slot2& X, float (&S)[4], float* ob,
                                           bool dostore, int tt) {
  float a = fmaf(X.k0.y, S[1], X.k0.x * S[0]) + fmaf(X.k0.w, S[3], X.k0.z * S[2]);
  float b = fmaf(X.q0.y, S[1], X.q0.x * S[0]) + fmaf(X.q0.w, S[3], X.q0.z * S[2]);
  float kS = red32(a);
  float qS = red32(b);
  float delta = fmaf(-X.bteg, kS, X.btv);   // bt*(v - eg*kS)
  S[0] = fmaf(X.k0.x, delta, X.eg * S[0]);
  S[1] = fmaf(X.k0.y, delta, X.eg * S[1]);
  S[2] = fmaf(X.k0.z, delta, X.eg * S[2]);
  S[3] = fmaf(X.k0.w, delta, X.eg * S[3]);
  if (dostore) ob[(size_t)tt * 2048] = fmaf(X.qk, delta, X.eg * qS);
}

__global__ void __launch_bounds__(64, 1) scan_kernel(const float* __restrict__ q,
                                                     const float* __restrict__ k,
                                                     const float* __restrict__ v,
                                                     const float4* __restrict__ g4,
                                                     float* __restrict__ o) {
  // 1024 blocks = 16 heads * 64 slices (2 v-cols each); b&7 = XCD swizzle
  const int b = blockIdx.x;
  const int xcd = b & 7, r = b >> 3;          // r: 0..127
  const int h = (xcd << 1) | (r >> 6);
  const int slice = r & 63;
  const int vbase = slice << 1;
  const int lane = threadIdx.x;
  const int kl = lane & 31, vl = lane >> 5;
  const float* kb = k + h * 128 + kl * 4;
  const float* qb = q + h * 128 + kl * 4;
  const float* vb = v + h * 128 + vbase + vl;
  const float4* g4b = g4 + h;
  float* ob = o + h * 128 + vbase + vl;
  const bool dostore = (kl == 0);
  float S[4] = {0, 0, 0, 0};
  Slot2 s0, s1, s2, s3, s4, s5, s6, s7;
  load_slot2(s0, kb, qb, vb, g4b, 0);
  load_slot2(s1, kb, qb, vb, g4b, 1);
  load_slot2(s2, kb, qb, vb, g4b, 2);
  load_slot2(s3, kb, qb, vb, g4b, 3);
  load_slot2(s4, kb, qb, vb, g4b, 4);
  load_slot2(s5, kb, qb, vb, g4b, 5);
  load_slot2(s6, kb, qb, vb, g4b, 6);
  load_slot2(s7, kb, qb, vb, g4b, 7);
  // prefetch past t=1023 lands in adjacent ws regions (in-bounds, unconsumed)
  for (int t = 0; t < 1024; t += 8) {
    step_slot2(s0, S, ob, dostore, t + 0); load_slot2(s0, kb, qb, vb, g4b, t + 8);
    step_slot2(s1, S, ob, dostore, t + 1); load_slot2(s1, kb, qb, vb, g4b, t + 9);
    step_slot2(s2, S, ob, dostore, t + 2); load_slot2(s2, kb, qb, vb, g4b, t + 10);
    step_slot2(s3, S, ob, dostore, t + 3); load_slot2(s3, kb, qb, vb, g4b, t + 11);
    step_slot2(s4, S, ob, dostore, t + 4); load_slot2(s4, kb, qb, vb, g4b, t + 12);
    step_slot2(s5, S, ob, dostore, t + 5); load_slot2(s5, kb, qb, vb, g4b, t + 13);
    step_slot2(s6, S, ob, dostore, t + 6); load_slot2(s6, kb, qb, vb, g4b, t + 14);
    step_slot2(s7, S, ob, dostore, t + 7); load_slot2(s7, kb, qb, vb, g4b, t + 15);
  }
}

// ---------- o_gated = bf16(rmsnorm_head(o)*w * silu(gate)) ----------
__global__ void __launch_bounds__(256) gate_o_kernel(const float* __restrict__ o,
                                                     const float* __restrict__ gate,
                                                     const float* __restrict__ onw,
                                                     unsigned short* __restrict__ ogb) {
  const int t = blockIdx.x, tid = threadIdx.x;
  const int c = tid << 3;
  const float* orow = o + (size_t)t * 2048 + c;
  float ov[8]; *(float4*)&ov[0] = *(const float4*)orow; *(float4*)&ov[4] = *(const float4*)(orow + 4);
  float ss = 0.f;
#pragma unroll
  for (int j = 0; j < 8; j++) ss += ov[j] * ov[j];
  ss = red16(ss);
  const float rn = rsqrtf(ss * (1.f / 128.f) + 1e-6f);
  const int dv = (tid & 15) << 3;
  float wv[8]; *(float4*)&wv[0] = *(const float4*)(onw + dv); *(float4*)&wv[4] = *(const float4*)(onw + dv + 4);
  const float* grow = gate + (size_t)t * 2048 + c;
  float gv[8]; *(float4*)&gv[0] = *(const float4*)grow; *(float4*)&gv[4] = *(const float4*)(grow + 4);
  u16x8 r;
#pragma unroll
  for (int j = 0; j < 8; j++) r[j] = f2bf(ov[j] * rn * wv[j] * silu_f(gv[j]));
  *(u16x8*)(ogb + (size_t)t * 2048 + c) = r;
}

// ---------- out = a + b + c ----------
__global__ void final_add3_kernel(const float* __restrict__ a, const float* __restrict__ b,
                                  const float* __restrict__ c, float* __restrict__ out) {
  const int NU = 1024 * 512;
  for (int u = blockIdx.x * blockDim.x + threadIdx.x; u < NU; u += gridDim.x * blockDim.x) {
    float4 va = ((const float4*)a)[u];
    float4 vb = ((const float4*)b)[u];
    float4 vc = ((const float4*)c)[u];
    va.x += vb.x + vc.x; va.y += vb.y + vc.y; va.z += vb.z + vc.z; va.w += vb.w + vc.w;
    ((float4*)out)[u] = va;
  }
}

// ---------- ws layout (bytes) ----------
constexpr size_t SZ_WQKVT   = (size_t)6144 * 2048 * 2;
constexpr size_t SZ_WSMALLT = (size_t)272 * 2048 * 2;
constexpr size_t SZ_WGBT    = (size_t)2048 * 128 * 2;
constexpr size_t SZ_WOT     = (size_t)2048 * 2048 * 2;
constexpr size_t SZ_WMLP1T  = (size_t)16384 * 2048 * 2;
constexpr size_t SZ_WDOWNT  = (size_t)2048 * 8192 * 2;
constexpr size_t OFF_WQKVT   = 0;
constexpr size_t OFF_WSMALLT = OFF_WQKVT + SZ_WQKVT;
constexpr size_t OFF_WGBT    = OFF_WSMALLT + SZ_WSMALLT;
constexpr size_t OFF_WOT     = OFF_WGBT + SZ_WGBT;
constexpr size_t OFF_WMLP1T  = OFF_WOT + SZ_WOT;
constexpr size_t OFF_WDOWNT  = OFF_WMLP1T + SZ_WMLP1T;
constexpr size_t A0          = OFF_WDOWNT + SZ_WDOWNT;
constexpr size_t OFF_HB    = A0;
constexpr size_t OFF_PROJ  = OFF_HB + (size_t)1024 * 2048 * 2;
constexpr size_t OFF_SMALL = OFF_PROJ + (size_t)1024 * 6144 * 4;
constexpr size_t OFF_Q     = OFF_SMALL + (size_t)1024 * 272 * 4;
constexpr size_t OFF_K     = OFF_Q + (size_t)1024 * 2048 * 4;
constexpr size_t OFF_V     = OFF_K + (size_t)1024 * 2048 * 4;
constexpr size_t OFF_G     = OFF_V + (size_t)1024 * 2048 * 4;   // scan over-read pad (64KB)
constexpr size_t OFF_BETA  = OFF_G + (size_t)1024 * 16 * 4;
constexpr size_t OFF_GAB   = OFF_BETA + (size_t)1024 * 16 * 4;
constexpr size_t OFF_GATE  = OFF_GAB + (size_t)1024 * 128 * 2;
constexpr size_t OFF_O     = OFF_GATE + (size_t)1024 * 2048 * 4;
constexpr size_t OFF_OGB   = OFF_O + (size_t)1024 * 2048 * 4;
constexpr size_t OFF_OPROJ = OFF_OGB + (size_t)1024 * 2048 * 2;
constexpr size_t OFF_X1    = OFF_OPROJ + (size_t)1024 * 2048 * 4;
constexpr size_t OFF_H2B   = OFF_X1 + (size_t)1024 * 2048 * 4;
constexpr size_t OFF_MID    = A0 + (size_t)1024 * 16384 * 4;   // overlaps dead GATE/O/OGB/OPROJ only
constexpr size_t OFF_MLPOUT = OFF_H2B + (size_t)1024 * 2048 * 2;
constexpr size_t OFF_QKB    = OFF_MLPOUT + (size_t)1024 * 2048 * 4;   // (unused, kept for layout)
constexpr size_t OFF_G4     = OFF_QKB + (size_t)1024 * 16 * 4;        // [1040][16] float4 (tail pad)
constexpr size_t OFF_MLPOUT2= OFF_G4 + (size_t)1040 * 16 * 16;
constexpr size_t WS_NEED    = OFF_MLPOUT2 + (size_t)1024 * 2048 * 4;
constexpr size_t OFF_OPROJ2 = OFF_O;   // liveness alias

extern "C" void kernel_launch(void* const* d_in, const int* in_sizes, int n_in,
                              void* d_out, int out_size, void* d_ws, size_t ws_size,
                              hipStream_t stream) {
  (void)in_sizes; (void)n_in; (void)out_size;
  const float* x     = (const float*)d_in[0];
  const float* wq    = (const float*)d_in[1];
  const float* wk    = (const float*)d_in[2];
  const float* wv    = (const float*)d_in[3];
  const float* cq    = (const float*)d_in[4];
  const float* ck    = (const float*)d_in[5];
  const float* cv    = (const float*)d_in[6];
  const float* wfa   = (const float*)d_in[7];
  const float* wfb   = (const float*)d_in[8];
  const float* wb    = (const float*)d_in[9];
  const float* wga   = (const float*)d_in[10];
  const float* wgb   = (const float*)d_in[11];
  const float* a_log = (const float*)d_in[12];
  const float* dtb   = (const float*)d_in[13];
  const float* onw   = (const float*)d_in[14];
  const float* wo    = (const float*)d_in[15];
  const float* ln1   = (const float*)d_in[16];
  const float* ln2   = (const float*)d_in[17];
  const float* wgate = (const float*)d_in[18];
  const float* wup   = (const float*)d_in[19];
  const float* wdown = (const float*)d_in[20];
  float* out = (float*)d_out;
  char* ws = (char*)d_ws;
  if (ws_size < WS_NEED) return;

  unsigned short* wqkvT   = (unsigned short*)(ws + OFF_WQKVT);
  unsigned short* wsmallT = (unsigned short*)(ws + OFF_WSMALLT);
  unsigned short* wgbT    = (unsigned short*)(ws + OFF_WGBT);
  unsigned short* woT     = (unsigned short*)(ws + OFF_WOT);
  unsigned short* wmlp1T  = (unsigned short*)(ws + OFF_WMLP1T);
  unsigned short* wdownT  = (unsigned short*)(ws + OFF_WDOWNT);
  unsigned short* hb      = (unsigned short*)(ws + OFF_HB);
  float* projf  = (float*)(ws + OFF_PROJ);
  float* smallf = (float*)(ws + OFF_SMALL);
  float* qf     = (float*)(ws + OFF_Q);
  float* kf     = (float*)(ws + OFF_K);
  float* vf     = (float*)(ws + OFF_V);
  unsigned short* gab = (unsigned short*)(ws + OFF_GAB);
  float* gatef  = (float*)(ws + OFF_GATE);
  float* of     = (float*)(ws + OFF_O);
  unsigned short* ogb = (unsigned short*)(ws + OFF_OGB);
  float* oprojf = (float*)(ws + OFF_OPROJ);
  float* oproj2f= (float*)(ws + OFF_OPROJ2);
  float* x1f    = (float*)(ws + OFF_X1);
  unsigned short* h2b = (unsigned short*)(ws + OFF_H2B);
  unsigned short* midb = (unsigned short*)(ws + OFF_MID);
  float* mlpoutf = (float*)(ws + OFF_MLPOUT);
  float* mlpout2f = (float*)(ws + OFF_MLPOUT2);
  float4* g4    = (float4*)(ws + OFF_G4);

  // --- one transpose launch for all 11 weights ---
  TDescs tds;
  int st = 0;
  auto set = [&](int i, const float* s, unsigned short* d, int R, int C) {
    int tx = (C + 63) / 64, ty = (R + 63) / 64;
    tds.d[i] = TDesc{s, d, R, C, tx, st};
    st += tx * ty;
  };
  set(0, wq, wqkvT, 2048, 2048);
  set(1, wk, wqkvT + (size_t)2048 * 2048, 2048, 2048);
  set(2, wv, wqkvT + (size_t)4096 * 2048, 2048, 2048);
  set(3, wfa, wsmallT, 2048, 128);
  set(4, wb, wsmallT + (size_t)128 * 2048, 2048, 16);
  set(5, wga, wsmallT + (size_t)144 * 2048, 2048, 128);
  set(6, wgb, wgbT, 128, 2048);
  set(7, wo, woT, 2048, 2048);
  set(8, wgate, wmlp1T, 2048, 8192);
  set(9, wup, wmlp1T + (size_t)8192 * 2048, 2048, 8192);
  set(10, wdown, wdownT, 8192, 2048);
  trans_all_kernel<<<st, 256, 0, stream>>>(tds);

  rmsnorm_bf16_kernel<<<1024, 256, 0, stream>>>(x, ln1, hb);
  gemm_bt_kernel<<<dim3(8, 48), 256, 0, stream>>>(hb, wqkvT, projf, 1024, 6144, 2048, 2048, 2048);
  gemm_bt_kernel<<<dim3(8, 3), 256, 0, stream>>>(hb, wsmallT, smallf, 1024, 272, 2048, 2048, 2048);
  conv_gates_kernel<<<1024, 256, 0, stream>>>(projf, cq, ck, cv, smallf, wfb, a_log, dtb,
                                              qf, kf, vf, g4, gab);
  gemm_bt_kernel<<<dim3(8, 16), 256, 0, stream>>>(gab, wgbT, gatef, 1024, 2048, 128, 128, 128);
  scan_kernel<<<1024, 64, 0, stream>>>(qf, kf, vf, g4, of);
  gate_o_kernel<<<1024, 256, 0, stream>>>(of, gatef, onw, ogb);
  gemm_bt_splitk2_kernel<<<dim3(8, 16, 2), 256, 0, stream>>>(ogb, woT, oprojf, oproj2f,
                                                             1024, 2048, 1024, 2048, 2048);
  add3_rmsnorm_kernel<<<1024, 256, 0, stream>>>(x, oprojf, oproj2f, ln2, x1f, h2b);
  gemm_dual_swiglu_kernel<<<dim3(8, 64), 256, 0, stream>>>(h2b, wmlp1T, midb);
  gemm_bt_splitk2_kernel<<<dim3(8, 16, 2), 256, 0, stream>>>(midb, wdownT, mlpoutf, mlpout2f,
                                                             1024, 2048, 4096, 8192, 8192);
  final_add3_kernel<<<2048, 256, 0, stream>>>(x1f, mlpoutf, mlpout2f, out);
}

// Round 12
// 737.940 us; speedup vs baseline: 1.1524x; 1.1524x over previous
//
#include <hip/hip_runtime.h>
#include <hip/hip_bf16.h>

typedef __attribute__((ext_vector_type(8))) short short8;
typedef __attribute__((ext_vector_type(4))) float f32x4;
typedef __attribute__((ext_vector_type(8))) unsigned short u16x8;
typedef __attribute__((ext_vector_type(4))) unsigned short u16x4;

// ---------- helpers ----------
__device__ __forceinline__ unsigned short f2bf(float f) {
  unsigned u = __float_as_uint(f);
  u += 0x7fffu + ((u >> 16) & 1u);          // round-to-nearest-even
  return (unsigned short)(u >> 16);
}
__device__ __forceinline__ float silu_f(float x) { return x / (1.f + __expf(-x)); }
__device__ __forceinline__ float red16(float v) {
  v += __shfl_xor(v, 1); v += __shfl_xor(v, 2);
  v += __shfl_xor(v, 4); v += __shfl_xor(v, 8);
  return v;
}
template <int CTRL>
__device__ __forceinline__ float dpp_mv(float v) {
  return __int_as_float(__builtin_amdgcn_update_dpp(0, __float_as_int(v), CTRL, 0xF, 0xF, true));
}
__device__ __forceinline__ float red16d(float v) {
  v += dpp_mv<0xB1>(v);   // quad_perm [1,0,3,2]
  v += dpp_mv<0x4E>(v);   // quad_perm [2,3,0,1]
  v += dpp_mv<0x141>(v);  // row_half_mirror
  v += dpp_mv<0x140>(v);  // row_mirror
  return v;
}
__device__ __forceinline__ void gload16(const void* g, void* l) {
  __builtin_amdgcn_global_load_lds((const __attribute__((address_space(1))) void*)g,
                                   (__attribute__((address_space(3))) void*)l, 16, 0, 0);
}

// ---------- ALL weight transposes in ONE launch (desc table) ----------
struct TDesc { const float* src; unsigned short* dst; int R, C, tilesX, start; };
struct TDescs { TDesc d[11]; };

__global__ void __launch_bounds__(256) trans_all_kernel(TDescs ds) {
  __shared__ float tile[64][65];   // tile[col'][row']
  const int bid = blockIdx.x;
  int e = 0;
#pragma unroll
  for (int i = 1; i < 11; i++) e = (bid >= ds.d[i].start) ? i : e;
  const float* __restrict__ src = ds.d[e].src;
  unsigned short* __restrict__ dst = ds.d[e].dst;
  const int R = ds.d[e].R, C = ds.d[e].C;
  const int local = bid - ds.d[e].start;
  const int c0 = (local % ds.d[e].tilesX) * 64;
  const int r0 = (local / ds.d[e].tilesX) * 64;
  const int tid = threadIdx.x;
  const int l = tid & 15, g = tid >> 4;
#pragma unroll
  for (int i = 0; i < 4; i++) {
    const int r = r0 + g + 16 * i;
    const int c = c0 + 4 * l;
    if (r < R) {
      if (c + 3 < C) {
        float4 v = *(const float4*)(src + (size_t)r * C + c);
        tile[4 * l + 0][g + 16 * i] = v.x;
        tile[4 * l + 1][g + 16 * i] = v.y;
        tile[4 * l + 2][g + 16 * i] = v.z;
        tile[4 * l + 3][g + 16 * i] = v.w;
      } else {
#pragma unroll
        for (int j = 0; j < 4; j++)
          if (c + j < C) tile[4 * l + j][g + 16 * i] = src[(size_t)r * C + c + j];
      }
    }
  }
  __syncthreads();
#pragma unroll
  for (int i = 0; i < 4; i++) {
    const int cc = c0 + g + 16 * i;
    const int rc = r0 + 4 * l;
    if (cc < C) {
      if (rc + 3 < R) {
        u16x4 o;
        o[0] = f2bf(tile[g + 16 * i][4 * l + 0]);
        o[1] = f2bf(tile[g + 16 * i][4 * l + 1]);
        o[2] = f2bf(tile[g + 16 * i][4 * l + 2]);
        o[3] = f2bf(tile[g + 16 * i][4 * l + 3]);
        *(u16x4*)(dst + (size_t)cc * R + rc) = o;
      } else {
#pragma unroll
        for (int j = 0; j < 4; j++)
          if (rc + j < R) dst[(size_t)cc * R + rc + j] = f2bf(tile[g + 16 * i][4 * l + j]);
      }
    }
  }
}

// ---------- rmsnorm (D=2048) -> bf16 ----------
__global__ void __launch_bounds__(256) rmsnorm_bf16_kernel(const float* __restrict__ x,
                                                           const float* __restrict__ w,
                                                           unsigned short* __restrict__ outb) {
  const int t = blockIdx.x, tid = threadIdx.x;
  const float* xr = x + (size_t)t * 2048 + tid * 8;
  float4 v0 = *(const float4*)xr, v1 = *(const float4*)(xr + 4);
  float ss = v0.x*v0.x + v0.y*v0.y + v0.z*v0.z + v0.w*v0.w
           + v1.x*v1.x + v1.y*v1.y + v1.z*v1.z + v1.w*v1.w;
#pragma unroll
  for (int m = 1; m < 64; m <<= 1) ss += __shfl_xor(ss, m);
  __shared__ float sb[4];
  if ((tid & 63) == 0) sb[tid >> 6] = ss;
  __syncthreads();
  float rn = rsqrtf((sb[0] + sb[1] + sb[2] + sb[3]) * (1.f / 2048.f) + 1e-6f);
  const float* wr = w + tid * 8;
  float4 w0 = *(const float4*)wr, w1 = *(const float4*)(wr + 4);
  u16x8 r;
  r[0]=f2bf(v0.x*rn*w0.x); r[1]=f2bf(v0.y*rn*w0.y); r[2]=f2bf(v0.z*rn*w0.z); r[3]=f2bf(v0.w*rn*w0.w);
  r[4]=f2bf(v1.x*rn*w1.x); r[5]=f2bf(v1.y*rn*w1.y); r[6]=f2bf(v1.z*rn*w1.z); r[7]=f2bf(v1.w*rn*w1.w);
  *(u16x8*)(outb + (size_t)t * 2048 + tid * 8) = r;
}

// ---------- x1 = x + y1 + y2 ; h2b = bf16(rmsnorm(x1)*w) ----------
__global__ void __launch_bounds__(256) add3_rmsnorm_kernel(const float* __restrict__ x,
                                                           const float* __restrict__ y1,
                                                           const float* __restrict__ y2,
                                                           const float* __restrict__ w,
                                                           float* __restrict__ x1,
                                                           unsigned short* __restrict__ h2b) {
  const int t = blockIdx.x, tid = threadIdx.x;
  const int c = tid * 8;
  const float* xr = x + (size_t)t * 2048 + c;
  const float* yr = y1 + (size_t)t * 2048 + c;
  const float* zr = y2 + (size_t)t * 2048 + c;
  float s[8]; float ss = 0.f;
  float4 a0 = *(const float4*)xr, a1 = *(const float4*)(xr + 4);
  float4 b0 = *(const float4*)yr, b1 = *(const float4*)(yr + 4);
  float4 c0 = *(const float4*)zr, c1 = *(const float4*)(zr + 4);
  s[0]=a0.x+b0.x+c0.x; s[1]=a0.y+b0.y+c0.y; s[2]=a0.z+b0.z+c0.z; s[3]=a0.w+b0.w+c0.w;
  s[4]=a1.x+b1.x+c1.x; s[5]=a1.y+b1.y+c1.y; s[6]=a1.z+b1.z+c1.z; s[7]=a1.w+b1.w+c1.w;
#pragma unroll
  for (int j = 0; j < 8; j++) ss += s[j] * s[j];
#pragma unroll
  for (int m = 1; m < 64; m <<= 1) ss += __shfl_xor(ss, m);
  __shared__ float sb[4];
  if ((tid & 63) == 0) sb[tid >> 6] = ss;
  __syncthreads();
  float rn = rsqrtf((sb[0] + sb[1] + sb[2] + sb[3]) * (1.f / 2048.f) + 1e-6f);
  float* xo = x1 + (size_t)t * 2048 + c;
  *(float4*)xo = *(float4*)&s[0];
  *(float4*)(xo + 4) = *(float4*)&s[4];
  const float* wr = w + c;
  float4 w0 = *(const float4*)wr, w1 = *(const float4*)(wr + 4);
  float wv[8] = {w0.x,w0.y,w0.z,w0.w,w1.x,w1.y,w1.z,w1.w};
  u16x8 r;
#pragma unroll
  for (int j = 0; j < 8; j++) r[j] = f2bf(s[j] * rn * wv[j]);
  *(u16x8*)(h2b + (size_t)t * 2048 + c) = r;
}

// ---------- bf16 GEMM: C[M,N] = A[M,K] * Bt[N,K]^T  (m97-style, strided) ----------
__global__ void __launch_bounds__(256) gemm_bt_kernel(const unsigned short* __restrict__ A,
                                                      const unsigned short* __restrict__ Bt,
                                                      float* __restrict__ C,
                                                      int M, int N, int K, int lda, int ldb) {
  __shared__ unsigned short As[128][32];
  __shared__ unsigned short Bs[128][32];
  const int tid = threadIdx.x;
  const int m0 = blockIdx.x << 7, n0 = blockIdx.y << 7;
  const int wave = tid >> 6, lane = tid & 63;
  const int wm = (wave >> 1) << 6, wn = (wave & 1) << 6;
  const int lrow = lane >> 2, lcol = lane & 3;
  const int ar0 = wave * 16 + lrow;
  const int ar1 = ar0 + 64;
  int br0 = n0 + ar0; br0 = br0 < N ? br0 : N - 1;
  int br1 = n0 + ar1; br1 = br1 < N ? br1 : N - 1;
  const unsigned short* Aptr0 = A + (size_t)(m0 + ar0) * lda + ((lcol ^ (ar0 & 3)) << 3);
  const unsigned short* Aptr1 = A + (size_t)(m0 + ar1) * lda + ((lcol ^ (ar1 & 3)) << 3);
  const unsigned short* Bptr0 = Bt + (size_t)br0 * ldb + ((lcol ^ (ar0 & 3)) << 3);
  const unsigned short* Bptr1 = Bt + (size_t)br1 * ldb + ((lcol ^ (ar1 & 3)) << 3);
  unsigned short* lA0 = &As[wave * 16][0];
  unsigned short* lA1 = &As[64 + wave * 16][0];
  unsigned short* lB0 = &Bs[wave * 16][0];
  unsigned short* lB1 = &Bs[64 + wave * 16][0];
  const int frow = lane & 15, fkb = lane >> 4;
  f32x4 acc[4][4];
#pragma unroll
  for (int i = 0; i < 4; i++)
#pragma unroll
    for (int j = 0; j < 4; j++) acc[i][j] = (f32x4){0.f, 0.f, 0.f, 0.f};

  for (int k0 = 0; k0 < K; k0 += 32) {
    gload16(Aptr0 + k0, lA0);
    gload16(Aptr1 + k0, lA1);
    gload16(Bptr0 + k0, lB0);
    gload16(Bptr1 + k0, lB1);
    __syncthreads();
    short8 af[4], bfr[4];
#pragma unroll
    for (int i = 0; i < 4; i++) {
      int ra = wm + i * 16 + frow;
      af[i] = *(const short8*)&As[ra][(fkb ^ (ra & 3)) << 3];
      int rb = wn + i * 16 + frow;
      bfr[i] = *(const short8*)&Bs[rb][(fkb ^ (rb & 3)) << 3];
    }
#pragma unroll
    for (int i = 0; i < 4; i++)
#pragma unroll
      for (int j = 0; j < 4; j++)
        acc[i][j] = __builtin_amdgcn_mfma_f32_16x16x32_bf16(af[i], bfr[j], acc[i][j], 0, 0, 0);
    __syncthreads();
  }
  const int crow = (lane >> 4) << 2, ccol = lane & 15;
#pragma unroll
  for (int i = 0; i < 4; i++) {
    const int gr = m0 + wm + i * 16 + crow;
#pragma unroll
    for (int j = 0; j < 4; j++) {
      const int gc = n0 + wn + j * 16 + ccol;
      if (gc < N) {
#pragma unroll
        for (int r = 0; r < 4; r++) C[(size_t)(gr + r) * N + gc] = acc[i][j][r];
      }
    }
  }
}

// ---------- split-K x2 GEMM in ONE launch: blockIdx.z picks K-half ----------
__global__ void __launch_bounds__(256) gemm_bt_splitk2_kernel(const unsigned short* __restrict__ Abase,
                                                              const unsigned short* __restrict__ Btbase,
                                                              float* __restrict__ C0,
                                                              float* __restrict__ C1,
                                                              int M, int N, int Khalf,
                                                              int lda, int ldb) {
  const unsigned short* A = Abase + (size_t)blockIdx.z * Khalf;
  const unsigned short* Bt = Btbase + (size_t)blockIdx.z * Khalf;
  float* C = blockIdx.z ? C1 : C0;
  __shared__ unsigned short As[128][32];
  __shared__ unsigned short Bs[128][32];
  const int tid = threadIdx.x;
  const int m0 = blockIdx.x << 7, n0 = blockIdx.y << 7;
  const int wave = tid >> 6, lane = tid & 63;
  const int wm = (wave >> 1) << 6, wn = (wave & 1) << 6;
  const int lrow = lane >> 2, lcol = lane & 3;
  const int ar0 = wave * 16 + lrow;
  const int ar1 = ar0 + 64;
  int br0 = n0 + ar0; br0 = br0 < N ? br0 : N - 1;
  int br1 = n0 + ar1; br1 = br1 < N ? br1 : N - 1;
  const unsigned short* Aptr0 = A + (size_t)(m0 + ar0) * lda + ((lcol ^ (ar0 & 3)) << 3);
  const unsigned short* Aptr1 = A + (size_t)(m0 + ar1) * lda + ((lcol ^ (ar1 & 3)) << 3);
  const unsigned short* Bptr0 = Bt + (size_t)br0 * ldb + ((lcol ^ (ar0 & 3)) << 3);
  const unsigned short* Bptr1 = Bt + (size_t)br1 * ldb + ((lcol ^ (ar1 & 3)) << 3);
  unsigned short* lA0 = &As[wave * 16][0];
  unsigned short* lA1 = &As[64 + wave * 16][0];
  unsigned short* lB0 = &Bs[wave * 16][0];
  unsigned short* lB1 = &Bs[64 + wave * 16][0];
  const int frow = lane & 15, fkb = lane >> 4;
  f32x4 acc[4][4];
#pragma unroll
  for (int i = 0; i < 4; i++)
#pragma unroll
    for (int j = 0; j < 4; j++) acc[i][j] = (f32x4){0.f, 0.f, 0.f, 0.f};

  for (int k0 = 0; k0 < Khalf; k0 += 32) {
    gload16(Aptr0 + k0, lA0);
    gload16(Aptr1 + k0, lA1);
    gload16(Bptr0 + k0, lB0);
    gload16(Bptr1 + k0, lB1);
    __syncthreads();
    short8 af[4], bfr[4];
#pragma unroll
    for (int i = 0; i < 4; i++) {
      int ra = wm + i * 16 + frow;
      af[i] = *(const short8*)&As[ra][(fkb ^ (ra & 3)) << 3];
      int rb = wn + i * 16 + frow;
      bfr[i] = *(const short8*)&Bs[rb][(fkb ^ (rb & 3)) << 3];
    }
#pragma unroll
    for (int i = 0; i < 4; i++)
#pragma unroll
      for (int j = 0; j < 4; j++)
        acc[i][j] = __builtin_amdgcn_mfma_f32_16x16x32_bf16(af[i], bfr[j], acc[i][j], 0, 0, 0);
    __syncthreads();
  }
  const int crow = (lane >> 4) << 2, ccol = lane & 15;
#pragma unroll
  for (int i = 0; i < 4; i++) {
    const int gr = m0 + wm + i * 16 + crow;
#pragma unroll
    for (int j = 0; j < 4; j++) {
      const int gc = n0 + wn + j * 16 + ccol;
      if (gc < N) {
#pragma unroll
        for (int r = 0; r < 4; r++) C[(size_t)(gr + r) * N + gc] = acc[i][j][r];
      }
    }
  }
}

// ---------- fused MLP1: mid = bf16(silu(A*B1t^T) * (A*B2t^T)), N=8192, K=2048 ----------
__global__ void __launch_bounds__(256) gemm_dual_swiglu_kernel(const unsigned short* __restrict__ A,
                                                               const unsigned short* __restrict__ Bt,
                                                               unsigned short* __restrict__ mid) {
  __shared__ unsigned short As[128][32];
  __shared__ unsigned short B1s[128][32];
  __shared__ unsigned short B2s[128][32];
  const int tid = threadIdx.x;
  const int m0 = blockIdx.x << 7, n0 = blockIdx.y << 7;
  const int wave = tid >> 6, lane = tid & 63;
  const int wm = (wave >> 1) << 6, wn = (wave & 1) << 6;
  const int lrow = lane >> 2, lcol = lane & 3;
  const int ar0 = wave * 16 + lrow;
  const int ar1 = ar0 + 64;
  const unsigned short* Aptr0 = A + (size_t)(m0 + ar0) * 2048 + ((lcol ^ (ar0 & 3)) << 3);
  const unsigned short* Aptr1 = A + (size_t)(m0 + ar1) * 2048 + ((lcol ^ (ar1 & 3)) << 3);
  const unsigned short* B1p0 = Bt + (size_t)(n0 + ar0) * 2048 + ((lcol ^ (ar0 & 3)) << 3);
  const unsigned short* B1p1 = Bt + (size_t)(n0 + ar1) * 2048 + ((lcol ^ (ar1 & 3)) << 3);
  const unsigned short* B2p0 = B1p0 + (size_t)8192 * 2048;
  const unsigned short* B2p1 = B1p1 + (size_t)8192 * 2048;
  unsigned short* lA0 = &As[wave * 16][0];
  unsigned short* lA1 = &As[64 + wave * 16][0];
  unsigned short* lB10 = &B1s[wave * 16][0];
  unsigned short* lB11 = &B1s[64 + wave * 16][0];
  unsigned short* lB20 = &B2s[wave * 16][0];
  unsigned short* lB21 = &B2s[64 + wave * 16][0];
  const int frow = lane & 15, fkb = lane >> 4;
  f32x4 acc1[4][4], acc2[4][4];
#pragma unroll
  for (int i = 0; i < 4; i++)
#pragma unroll
    for (int j = 0; j < 4; j++) {
      acc1[i][j] = (f32x4){0.f, 0.f, 0.f, 0.f};
      acc2[i][j] = (f32x4){0.f, 0.f, 0.f, 0.f};
    }
  for (int k0 = 0; k0 < 2048; k0 += 32) {
    gload16(Aptr0 + k0, lA0);
    gload16(Aptr1 + k0, lA1);
    gload16(B1p0 + k0, lB10);
    gload16(B1p1 + k0, lB11);
    gload16(B2p0 + k0, lB20);
    gload16(B2p1 + k0, lB21);
    __syncthreads();
    short8 af[4], b1f[4], b2f[4];
#pragma unroll
    for (int i = 0; i < 4; i++) {
      int ra = wm + i * 16 + frow;
      af[i] = *(const short8*)&As[ra][(fkb ^ (ra & 3)) << 3];
      int rb = wn + i * 16 + frow;
      b1f[i] = *(const short8*)&B1s[rb][(fkb ^ (rb & 3)) << 3];
      b2f[i] = *(const short8*)&B2s[rb][(fkb ^ (rb & 3)) << 3];
    }
#pragma unroll
    for (int i = 0; i < 4; i++)
#pragma unroll
      for (int j = 0; j < 4; j++) {
        acc1[i][j] = __builtin_amdgcn_mfma_f32_16x16x32_bf16(af[i], b1f[j], acc1[i][j], 0, 0, 0);
        acc2[i][j] = __builtin_amdgcn_mfma_f32_16x16x32_bf16(af[i], b2f[j], acc2[i][j], 0, 0, 0);
      }
    __syncthreads();
  }
  const int crow = (lane >> 4) << 2, ccol = lane & 15;
#pragma unroll
  for (int i = 0; i < 4; i++) {
    const int gr = m0 + wm + i * 16 + crow;
#pragma unroll
    for (int j = 0; j < 4; j++) {
      const int gc = n0 + wn + j * 16 + ccol;
#pragma unroll
      for (int r = 0; r < 4; r++)
        mid[(size_t)(gr + r) * 8192 + gc] = f2bf(silu_f(acc1[i][j][r]) * acc2[i][j][r]);
    }
  }
}

// ---------- MERGED: causal dwconv + silu + l2norm + qk dot + gates ----------
__global__ void __launch_bounds__(256) conv_gates_kernel(const float* __restrict__ proj,
                                                         const float* __restrict__ cq,
                                                         const float* __restrict__ ck,
                                                         const float* __restrict__ cv,
                                                         const float* __restrict__ small,
                                                         const float* __restrict__ wfb,
                                                         const float* __restrict__ a_log,
                                                         const float* __restrict__ dtb,
                                                         float* __restrict__ q, float* __restrict__ k,
                                                         float* __restrict__ v,
                                                         float4* __restrict__ g4,
                                                         unsigned short* __restrict__ gab) {
  __shared__ float qksh[16];
  const int t = blockIdx.x, tid = threadIdx.x;
  const int c = tid << 3;
  float aq[8] = {0,0,0,0,0,0,0,0}, ak[8] = {0,0,0,0,0,0,0,0}, av[8] = {0,0,0,0,0,0,0,0};
#pragma unroll
  for (int i = 0; i < 4; i++) {
    const int tt = t + i - 3;
    if (tt < 0) continue;
    const float* pr = proj + (size_t)tt * 6144;
    float pq[8], pk[8], pv[8], w0[8], w1[8], w2[8];
    *(float4*)&pq[0] = *(const float4*)(pr + c);        *(float4*)&pq[4] = *(const float4*)(pr + c + 4);
    *(float4*)&pk[0] = *(const float4*)(pr + 2048 + c); *(float4*)&pk[4] = *(const float4*)(pr + 2048 + c + 4);
    *(float4*)&pv[0] = *(const float4*)(pr + 4096 + c); *(float4*)&pv[4] = *(const float4*)(pr + 4096 + c + 4);
    *(float4*)&w0[0] = *(const float4*)(cq + i * 2048 + c); *(float4*)&w0[4] = *(const float4*)(cq + i * 2048 + c + 4);
    *(float4*)&w1[0] = *(const float4*)(ck + i * 2048 + c); *(float4*)&w1[4] = *(const float4*)(ck + i * 2048 + c + 4);
    *(float4*)&w2[0] = *(const float4*)(cv + i * 2048 + c); *(float4*)&w2[4] = *(const float4*)(cv + i * 2048 + c + 4);
#pragma unroll
    for (int j = 0; j < 8; j++) { aq[j] += w0[j]*pq[j]; ak[j] += w1[j]*pk[j]; av[j] += w2[j]*pv[j]; }
  }
  float sq[8], sk[8], sv[8]; float ssq = 0.f, ssk = 0.f;
#pragma unroll
  for (int j = 0; j < 8; j++) {
    sq[j] = silu_f(aq[j]); ssq += sq[j]*sq[j];
    sk[j] = silu_f(ak[j]); ssk += sk[j]*sk[j];
    sv[j] = silu_f(av[j]);
  }
  ssq = red16(ssq); ssk = red16(ssk);
  const float rq = rsqrtf(ssq + 1e-6f) * 0.08838834764831845f;  // * DK^-0.5
  const float rk = rsqrtf(ssk + 1e-6f);
  float oq[8], ok[8]; float qkl = 0.f;
#pragma unroll
  for (int j = 0; j < 8; j++) { oq[j] = sq[j]*rq; ok[j] = sk[j]*rk; qkl += oq[j]*ok[j]; }
  qkl = red16(qkl);
  if ((tid & 15) == 0) qksh[tid >> 4] = qkl;
  float* qo = q + (size_t)t * 2048 + c;
  *(float4*)qo = *(float4*)&oq[0]; *(float4*)(qo + 4) = *(float4*)&oq[4];
  float* ko = k + (size_t)t * 2048 + c;
  *(float4*)ko = *(float4*)&ok[0]; *(float4*)(ko + 4) = *(float4*)&ok[4];
  float* vo = v + (size_t)t * 2048 + c;
  *(float4*)vo = *(float4*)&sv[0]; *(float4*)(vo + 4) = *(float4*)&sv[4];
  __syncthreads();
  if (tid < 128) {
    const float* srow = small + (size_t)t * 272;
    const int hh = tid >> 3, j = tid & 7;
    float d = 0.f;
#pragma unroll
    for (int i = 0; i < 16; i++) d += srow[j * 16 + i] * wfb[(j * 16 + i) * 16 + hh];
    d += __shfl_xor(d, 1); d += __shfl_xor(d, 2); d += __shfl_xor(d, 4);
    if (j == 0) {
      d += dtb[hh];
      float sp = (d > 20.f) ? d : log1pf(expf(d));
      float eg = expf(-expf(a_log[hh]) * sp);
      float bt = 1.f / (1.f + expf(-srow[128 + hh]));
      g4[t * 16 + hh] = make_float4(eg, bt, qksh[hh], 0.f);
    }
    gab[(size_t)t * 128 + tid] = f2bf(srow[144 + tid]);
  }
}

// ---------- gated delta-rule scan (round-3 known-good: 8x20-reg slots) ----------
struct Slot { float4 k0, k1, q0, q1; float eg, qk, btv, bteg; };

__device__ __forceinline__ void load_slot(Slot& X, const float* kb, const float* qb,
                                          const float* vb, const float4* g4b, int tt) {
  const float* kp = kb + (size_t)tt * 2048;
  const float* qp = qb + (size_t)tt * 2048;
  X.k0 = *(const float4*)kp; X.k1 = *(const float4*)(kp + 4);
  X.q0 = *(const float4*)qp; X.q1 = *(const float4*)(qp + 4);
  float4 g = g4b[(size_t)tt * 16];
  float v = vb[(size_t)tt * 2048];
  X.eg = g.x; X.qk = g.z;
  X.btv = g.y * v;            // off-chain precompute
  X.bteg = g.y * g.x;
}

__device__ __forceinline__ void step_slot(const Slot& X, float (&S)[8], float* ob,
                                          bool dostore, int tt) {
  float a0 = fmaf(X.k1.x, S[4], X.k0.x * S[0]);
  float a1 = fmaf(X.k1.y, S[5], X.k0.y * S[1]);
  float a2 = fmaf(X.k1.z, S[6], X.k0.z * S[2]);
  float a3 = fmaf(X.k1.w, S[7], X.k0.w * S[3]);
  float b0 = fmaf(X.q1.x, S[4], X.q0.x * S[0]);
  float b1 = fmaf(X.q1.y, S[5], X.q0.y * S[1]);
  float b2 = fmaf(X.q1.z, S[6], X.q0.z * S[2]);
  float b3 = fmaf(X.q1.w, S[7], X.q0.w * S[3]);
  float kS = red16d((a0 + a1) + (a2 + a3));
  float qS = red16d((b0 + b1) + (b2 + b3));
  float delta = fmaf(-X.bteg, kS, X.btv);   // bt*(v - eg*kS)
  S[0] = fmaf(X.k0.x, delta, X.eg * S[0]);
  S[1] = fmaf(X.k0.y, delta, X.eg * S[1]);
  S[2] = fmaf(X.k0.z, delta, X.eg * S[2]);
  S[3] = fmaf(X.k0.w, delta, X.eg * S[3]);
  S[4] = fmaf(X.k1.x, delta, X.eg * S[4]);
  S[5] = fmaf(X.k1.y, delta, X.eg * S[5]);
  S[6] = fmaf(X.k1.z, delta, X.eg * S[6]);
  S[7] = fmaf(X.k1.w, delta, X.eg * S[7]);
  if (dostore) ob[(size_t)tt * 2048] = fmaf(X.qk, delta, X.eg * qS);
}

__global__ void __launch_bounds__(64, 1) scan_kernel(const float* __restrict__ q,
                                                     const float* __restrict__ k,
                                                     const float* __restrict__ v,
                                                     const float4* __restrict__ g4,
                                                     float* __restrict__ o) {
  // XCD swizzle: b&7 = XCD -> heads 2x,2x+1 stay on one XCD
  const int b = blockIdx.x;            // 512 = 16 heads * 32 slices
  const int xcd = b & 7, r = b >> 3;
  const int h = (xcd << 1) | (r >> 5);
  const int vbase = (r & 31) << 2;
  const int lane = threadIdx.x;
  const int kl = lane & 15, vl = lane >> 4;
  const int vcol = vbase + vl;
  const int koff = h * 128 + kl * 8;
  const int voff = h * 128 + vcol;
  const float* kb = k + koff;
  const float* qb = q + koff;
  const float* vb = v + voff;
  const float4* g4b = g4 + h;
  float* ob = o + voff;
  const bool dostore = (kl == 0);
  float S[8] = {0,0,0,0,0,0,0,0};
  Slot s0, s1, s2, s3, s4, s5, s6, s7;
  load_slot(s0, kb, qb, vb, g4b, 0);
  load_slot(s1, kb, qb, vb, g4b, 1);
  load_slot(s2, kb, qb, vb, g4b, 2);
  load_slot(s3, kb, qb, vb, g4b, 3);
  load_slot(s4, kb, qb, vb, g4b, 4);
  load_slot(s5, kb, qb, vb, g4b, 5);
  load_slot(s6, kb, qb, vb, g4b, 6);
  load_slot(s7, kb, qb, vb, g4b, 7);
  // prefetch reads past t=1023 land in adjacent ws regions (in-bounds, unconsumed)
  for (int t = 0; t < 1024; t += 8) {
    step_slot(s0, S, ob, dostore, t + 0); load_slot(s0, kb, qb, vb, g4b, t + 8);
    step_slot(s1, S, ob, dostore, t + 1); load_slot(s1, kb, qb, vb, g4b, t + 9);
    step_slot(s2, S, ob, dostore, t + 2); load_slot(s2, kb, qb, vb, g4b, t + 10);
    step_slot(s3, S, ob, dostore, t + 3); load_slot(s3, kb, qb, vb, g4b, t + 11);
    step_slot(s4, S, ob, dostore, t + 4); load_slot(s4, kb, qb, vb, g4b, t + 12);
    step_slot(s5, S, ob, dostore, t + 5); load_slot(s5, kb, qb, vb, g4b, t + 13);
    step_slot(s6, S, ob, dostore, t + 6); load_slot(s6, kb, qb, vb, g4b, t + 14);
    step_slot(s7, S, ob, dostore, t + 7); load_slot(s7, kb, qb, vb, g4b, t + 15);
  }
}

// ---------- o_gated = bf16(rmsnorm_head(o)*w * silu(gate)) ----------
__global__ void __launch_bounds__(256) gate_o_kernel(const float* __restrict__ o,
                                                     const float* __restrict__ gate,
                                                     const float* __restrict__ onw,
                                                     unsigned short* __restrict__ ogb) {
  const int t = blockIdx.x, tid = threadIdx.x;
  const int c = tid << 3;
  const float* orow = o + (size_t)t * 2048 + c;
  float ov[8]; *(float4*)&ov[0] = *(const float4*)orow; *(float4*)&ov[4] = *(const float4*)(orow + 4);
  float ss = 0.f;
#pragma unroll
  for (int j = 0; j < 8; j++) ss += ov[j] * ov[j];
  ss = red16(ss);
  const float rn = rsqrtf(ss * (1.f / 128.f) + 1e-6f);
  const int dv = (tid & 15) << 3;
  float wv[8]; *(float4*)&wv[0] = *(const float4*)(onw + dv); *(float4*)&wv[4] = *(const float4*)(onw + dv + 4);
  const float* grow = gate + (size_t)t * 2048 + c;
  float gv[8]; *(float4*)&gv[0] = *(const float4*)grow; *(float4*)&gv[4] = *(const float4*)(grow + 4);
  u16x8 r;
#pragma unroll
  for (int j = 0; j < 8; j++) r[j] = f2bf(ov[j] * rn * wv[j] * silu_f(gv[j]));
  *(u16x8*)(ogb + (size_t)t * 2048 + c) = r;
}

// ---------- out = a + b + c ----------
__global__ void final_add3_kernel(const float* __restrict__ a, const float* __restrict__ b,
                                  const float* __restrict__ c, float* __restrict__ out) {
  const int NU = 1024 * 512;
  for (int u = blockIdx.x * blockDim.x + threadIdx.x; u < NU; u += gridDim.x * blockDim.x) {
    float4 va = ((const float4*)a)[u];
    float4 vb = ((const float4*)b)[u];
    float4 vc = ((const float4*)c)[u];
    va.x += vb.x + vc.x; va.y += vb.y + vc.y; va.z += vb.z + vc.z; va.w += vb.w + vc.w;
    ((float4*)out)[u] = va;
  }
}

// ---------- ws layout (bytes) ----------
constexpr size_t SZ_WQKVT   = (size_t)6144 * 2048 * 2;
constexpr size_t SZ_WSMALLT = (size_t)272 * 2048 * 2;
constexpr size_t SZ_WGBT    = (size_t)2048 * 128 * 2;
constexpr size_t SZ_WOT     = (size_t)2048 * 2048 * 2;
constexpr size_t SZ_WMLP1T  = (size_t)16384 * 2048 * 2;
constexpr size_t SZ_WDOWNT  = (size_t)2048 * 8192 * 2;
constexpr size_t OFF_WQKVT   = 0;
constexpr size_t OFF_WSMALLT = OFF_WQKVT + SZ_WQKVT;
constexpr size_t OFF_WGBT    = OFF_WSMALLT + SZ_WSMALLT;
constexpr size_t OFF_WOT     = OFF_WGBT + SZ_WGBT;
constexpr size_t OFF_WMLP1T  = OFF_WOT + SZ_WOT;
constexpr size_t OFF_WDOWNT  = OFF_WMLP1T + SZ_WMLP1T;
constexpr size_t A0          = OFF_WDOWNT + SZ_WDOWNT;
constexpr size_t OFF_HB    = A0;
constexpr size_t OFF_PROJ  = OFF_HB + (size_t)1024 * 2048 * 2;
constexpr size_t OFF_SMALL = OFF_PROJ + (size_t)1024 * 6144 * 4;
constexpr size_t OFF_Q     = OFF_SMALL + (size_t)1024 * 272 * 4;
constexpr size_t OFF_K     = OFF_Q + (size_t)1024 * 2048 * 4;
constexpr size_t OFF_V     = OFF_K + (size_t)1024 * 2048 * 4;
constexpr size_t OFF_G     = OFF_V + (size_t)1024 * 2048 * 4;   // scan over-read pad
constexpr size_t OFF_BETA  = OFF_G + (size_t)1024 * 16 * 4;
constexpr size_t OFF_GAB   = OFF_BETA + (size_t)1024 * 16 * 4;
constexpr size_t OFF_GATE  = OFF_GAB + (size_t)1024 * 128 * 2;
constexpr size_t OFF_O     = OFF_GATE + (size_t)1024 * 2048 * 4;
constexpr size_t OFF_OGB   = OFF_O + (size_t)1024 * 2048 * 4;
constexpr size_t OFF_OPROJ = OFF_OGB + (size_t)1024 * 2048 * 2;
constexpr size_t OFF_X1    = OFF_OPROJ + (size_t)1024 * 2048 * 4;
constexpr size_t OFF_H2B   = OFF_X1 + (size_t)1024 * 2048 * 4;
constexpr size_t OFF_MID    = A0 + (size_t)1024 * 16384 * 4;   // overlaps dead GATE/O/OGB/OPROJ only
constexpr size_t OFF_MLPOUT = OFF_H2B + (size_t)1024 * 2048 * 2;
constexpr size_t OFF_QKB    = OFF_MLPOUT + (size_t)1024 * 2048 * 4;   // (unused, layout keep)
constexpr size_t OFF_G4     = OFF_QKB + (size_t)1024 * 16 * 4;        // [1040][16] float4 (tail pad)
constexpr size_t OFF_MLPOUT2= OFF_G4 + (size_t)1040 * 16 * 16;
constexpr size_t WS_NEED    = OFF_MLPOUT2 + (size_t)1024 * 2048 * 4;
constexpr size_t OFF_OPROJ2 = OFF_O;   // liveness alias

extern "C" void kernel_launch(void* const* d_in, const int* in_sizes, int n_in,
                              void* d_out, int out_size, void* d_ws, size_t ws_size,
                              hipStream_t stream) {
  (void)in_sizes; (void)n_in; (void)out_size;
  const float* x     = (const float*)d_in[0];
  const float* wq    = (const float*)d_in[1];
  const float* wk    = (const float*)d_in[2];
  const float* wv    = (const float*)d_in[3];
  const float* cq    = (const float*)d_in[4];
  const float* ck    = (const float*)d_in[5];
  const float* cv    = (const float*)d_in[6];
  const float* wfa   = (const float*)d_in[7];
  const float* wfb   = (const float*)d_in[8];
  const float* wb    = (const float*)d_in[9];
  const float* wga   = (const float*)d_in[10];
  const float* wgb   = (const float*)d_in[11];
  const float* a_log = (const float*)d_in[12];
  const float* dtb   = (const float*)d_in[13];
  const float* onw   = (const float*)d_in[14];
  const float* wo    = (const float*)d_in[15];
  const float* ln1   = (const float*)d_in[16];
  const float* ln2   = (const float*)d_in[17];
  const float* wgate = (const float*)d_in[18];
  const float* wup   = (const float*)d_in[19];
  const float* wdown = (const float*)d_in[20];
  float* out = (float*)d_out;
  char* ws = (char*)d_ws;
  if (ws_size < WS_NEED) return;

  unsigned short* wqkvT   = (unsigned short*)(ws + OFF_WQKVT);
  unsigned short* wsmallT = (unsigned short*)(ws + OFF_WSMALLT);
  unsigned short* wgbT    = (unsigned short*)(ws + OFF_WGBT);
  unsigned short* woT     = (unsigned short*)(ws + OFF_WOT);
  unsigned short* wmlp1T  = (unsigned short*)(ws + OFF_WMLP1T);
  unsigned short* wdownT  = (unsigned short*)(ws + OFF_WDOWNT);
  unsigned short* hb      = (unsigned short*)(ws + OFF_HB);
  float* projf  = (float*)(ws + OFF_PROJ);
  float* smallf = (float*)(ws + OFF_SMALL);
  float* qf     = (float*)(ws + OFF_Q);
  float* kf     = (float*)(ws + OFF_K);
  float* vf     = (float*)(ws + OFF_V);
  unsigned short* gab = (unsigned short*)(ws + OFF_GAB);
  float* gatef  = (float*)(ws + OFF_GATE);
  float* of     = (float*)(ws + OFF_O);
  unsigned short* ogb = (unsigned short*)(ws + OFF_OGB);
  float* oprojf = (float*)(ws + OFF_OPROJ);
  float* oproj2f= (float*)(ws + OFF_OPROJ2);
  float* x1f    = (float*)(ws + OFF_X1);
  unsigned short* h2b = (unsigned short*)(ws + OFF_H2B);
  unsigned short* midb = (unsigned short*)(ws + OFF_MID);
  float* mlpoutf = (float*)(ws + OFF_MLPOUT);
  float* mlpout2f = (float*)(ws + OFF_MLPOUT2);
  float4* g4    = (float4*)(ws + OFF_G4);

  // --- one transpose launch for all 11 weights ---
  TDescs tds;
  int st = 0;
  auto set = [&](int i, const float* s, unsigned short* d, int R, int C) {
    int tx = (C + 63) / 64, ty = (R + 63) / 64;
    tds.d[i] = TDesc{s, d, R, C, tx, st};
    st += tx * ty;
  };
  set(0, wq, wqkvT, 2048, 2048);
  set(1, wk, wqkvT + (size_t)2048 * 2048, 2048, 2048);
  set(2, wv, wqkvT + (size_t)4096 * 2048, 2048, 2048);
  set(3, wfa, wsmallT, 2048, 128);
  set(4, wb, wsmallT + (size_t)128 * 2048, 2048, 16);
  set(5, wga, wsmallT + (size_t)144 * 2048, 2048, 128);
  set(6, wgb, wgbT, 128, 2048);
  set(7, wo, woT, 2048, 2048);
  set(8, wgate, wmlp1T, 2048, 8192);
  set(9, wup, wmlp1T + (size_t)8192 * 2048, 2048, 8192);
  set(10, wdown, wdownT, 8192, 2048);
  trans_all_kernel<<<st, 256, 0, stream>>>(tds);

  rmsnorm_bf16_kernel<<<1024, 256, 0, stream>>>(x, ln1, hb);
  gemm_bt_kernel<<<dim3(8, 48), 256, 0, stream>>>(hb, wqkvT, projf, 1024, 6144, 2048, 2048, 2048);
  gemm_bt_kernel<<<dim3(8, 3), 256, 0, stream>>>(hb, wsmallT, smallf, 1024, 272, 2048, 2048, 2048);
  conv_gates_kernel<<<1024, 256, 0, stream>>>(projf, cq, ck, cv, smallf, wfb, a_log, dtb,
                                              qf, kf, vf, g4, gab);
  gemm_bt_kernel<<<dim3(8, 16), 256, 0, stream>>>(gab, wgbT, gatef, 1024, 2048, 128, 128, 128);
  scan_kernel<<<512, 64, 0, stream>>>(qf, kf, vf, g4, of);
  gate_o_kernel<<<1024, 256, 0, stream>>>(of, gatef, onw, ogb);
  gemm_bt_splitk2_kernel<<<dim3(8, 16, 2), 256, 0, stream>>>(ogb, woT, oprojf, oproj2f,
                                                             1024, 2048, 1024, 2048, 2048);
  add3_rmsnorm_kernel<<<1024, 256, 0, stream>>>(x, oprojf, oproj2f, ln2, x1f, h2b);
  gemm_dual_swiglu_kernel<<<dim3(8, 64), 256, 0, stream>>>(h2b, wmlp1T, midb);
  gemm_bt_splitk2_kernel<<<dim3(8, 16, 2), 256, 0, stream>>>(midb, wdownT, mlpoutf, mlpout2f,
                                                             1024, 2048, 4096, 8192, 8192);
  final_add3_kernel<<<2048, 256, 0, stream>>>(x1f, mlpoutf, mlpout2f, out);
}

// Round 13
// 699.019 us; speedup vs baseline: 1.2165x; 1.0557x over previous
//
#include <hip/hip_runtime.h>
#include <hip/hip_bf16.h>

typedef __attribute__((ext_vector_type(8))) short short8;
typedef __attribute__((ext_vector_type(4))) float f32x4;
typedef __attribute__((ext_vector_type(8))) unsigned short u16x8;
typedef __attribute__((ext_vector_type(4))) unsigned short u16x4;

// ---------- helpers ----------
__device__ __forceinline__ unsigned short f2bf(float f) {
  unsigned u = __float_as_uint(f);
  u += 0x7fffu + ((u >> 16) & 1u);          // round-to-nearest-even
  return (unsigned short)(u >> 16);
}
__device__ __forceinline__ float silu_f(float x) { return x / (1.f + __expf(-x)); }
__device__ __forceinline__ float red16(float v) {
  v += __shfl_xor(v, 1); v += __shfl_xor(v, 2);
  v += __shfl_xor(v, 4); v += __shfl_xor(v, 8);
  return v;
}
template <int CTRL>
__device__ __forceinline__ float dpp_mv(float v) {
  return __int_as_float(__builtin_amdgcn_update_dpp(0, __float_as_int(v), CTRL, 0xF, 0xF, true));
}
__device__ __forceinline__ float red16d(float v) {
  v += dpp_mv<0xB1>(v);   // quad_perm [1,0,3,2]
  v += dpp_mv<0x4E>(v);   // quad_perm [2,3,0,1]
  v += dpp_mv<0x141>(v);  // row_half_mirror
  v += dpp_mv<0x140>(v);  // row_mirror
  return v;
}
__device__ __forceinline__ void gload16(const void* g, void* l) {
  __builtin_amdgcn_global_load_lds((const __attribute__((address_space(1))) void*)g,
                                   (__attribute__((address_space(3))) void*)l, 16, 0, 0);
}

// ---------- ALL weight transposes in ONE launch (desc table) ----------
struct TDesc { const float* src; unsigned short* dst; int R, C, tilesX, start; };
struct TDescs { TDesc d[11]; };

__global__ void __launch_bounds__(256) trans_all_kernel(TDescs ds) {
  __shared__ float tile[64][65];   // tile[col'][row']
  const int bid = blockIdx.x;
  int e = 0;
#pragma unroll
  for (int i = 1; i < 11; i++) e = (bid >= ds.d[i].start) ? i : e;
  const float* __restrict__ src = ds.d[e].src;
  unsigned short* __restrict__ dst = ds.d[e].dst;
  const int R = ds.d[e].R, C = ds.d[e].C;
  const int local = bid - ds.d[e].start;
  const int c0 = (local % ds.d[e].tilesX) * 64;
  const int r0 = (local / ds.d[e].tilesX) * 64;
  const int tid = threadIdx.x;
  const int l = tid & 15, g = tid >> 4;
#pragma unroll
  for (int i = 0; i < 4; i++) {
    const int r = r0 + g + 16 * i;
    const int c = c0 + 4 * l;
    if (r < R) {
      if (c + 3 < C) {
        float4 v = *(const float4*)(src + (size_t)r * C + c);
        tile[4 * l + 0][g + 16 * i] = v.x;
        tile[4 * l + 1][g + 16 * i] = v.y;
        tile[4 * l + 2][g + 16 * i] = v.z;
        tile[4 * l + 3][g + 16 * i] = v.w;
      } else {
#pragma unroll
        for (int j = 0; j < 4; j++)
          if (c + j < C) tile[4 * l + j][g + 16 * i] = src[(size_t)r * C + c + j];
      }
    }
  }
  __syncthreads();
#pragma unroll
  for (int i = 0; i < 4; i++) {
    const int cc = c0 + g + 16 * i;
    const int rc = r0 + 4 * l;
    if (cc < C) {
      if (rc + 3 < R) {
        u16x4 o;
        o[0] = f2bf(tile[g + 16 * i][4 * l + 0]);
        o[1] = f2bf(tile[g + 16 * i][4 * l + 1]);
        o[2] = f2bf(tile[g + 16 * i][4 * l + 2]);
        o[3] = f2bf(tile[g + 16 * i][4 * l + 3]);
        *(u16x4*)(dst + (size_t)cc * R + rc) = o;
      } else {
#pragma unroll
        for (int j = 0; j < 4; j++)
          if (rc + j < R) dst[(size_t)cc * R + rc + j] = f2bf(tile[g + 16 * i][4 * l + j]);
      }
    }
  }
}

// ---------- rmsnorm (D=2048) -> bf16 ----------
__global__ void __launch_bounds__(256) rmsnorm_bf16_kernel(const float* __restrict__ x,
                                                           const float* __restrict__ w,
                                                           unsigned short* __restrict__ outb) {
  const int t = blockIdx.x, tid = threadIdx.x;
  const float* xr = x + (size_t)t * 2048 + tid * 8;
  float4 v0 = *(const float4*)xr, v1 = *(const float4*)(xr + 4);
  float ss = v0.x*v0.x + v0.y*v0.y + v0.z*v0.z + v0.w*v0.w
           + v1.x*v1.x + v1.y*v1.y + v1.z*v1.z + v1.w*v1.w;
#pragma unroll
  for (int m = 1; m < 64; m <<= 1) ss += __shfl_xor(ss, m);
  __shared__ float sb[4];
  if ((tid & 63) == 0) sb[tid >> 6] = ss;
  __syncthreads();
  float rn = rsqrtf((sb[0] + sb[1] + sb[2] + sb[3]) * (1.f / 2048.f) + 1e-6f);
  const float* wr = w + tid * 8;
  float4 w0 = *(const float4*)wr, w1 = *(const float4*)(wr + 4);
  u16x8 r;
  r[0]=f2bf(v0.x*rn*w0.x); r[1]=f2bf(v0.y*rn*w0.y); r[2]=f2bf(v0.z*rn*w0.z); r[3]=f2bf(v0.w*rn*w0.w);
  r[4]=f2bf(v1.x*rn*w1.x); r[5]=f2bf(v1.y*rn*w1.y); r[6]=f2bf(v1.z*rn*w1.z); r[7]=f2bf(v1.w*rn*w1.w);
  *(u16x8*)(outb + (size_t)t * 2048 + tid * 8) = r;
}

// ---------- x1 = x + y1..y4 ; h2b = bf16(rmsnorm(x1)*w) ----------
__global__ void __launch_bounds__(256) add5_rmsnorm_kernel(const float* __restrict__ x,
                                                           const float* __restrict__ y1,
                                                           const float* __restrict__ y2,
                                                           const float* __restrict__ y3,
                                                           const float* __restrict__ y4,
                                                           const float* __restrict__ w,
                                                           float* __restrict__ x1,
                                                           unsigned short* __restrict__ h2b) {
  const int t = blockIdx.x, tid = threadIdx.x;
  const int c = tid * 8;
  const size_t off = (size_t)t * 2048 + c;
  float s[8]; float ss = 0.f;
  float4 a0 = *(const float4*)(x + off),  a1 = *(const float4*)(x + off + 4);
  float4 b0 = *(const float4*)(y1 + off), b1 = *(const float4*)(y1 + off + 4);
  float4 c0 = *(const float4*)(y2 + off), c1 = *(const float4*)(y2 + off + 4);
  float4 d0 = *(const float4*)(y3 + off), d1 = *(const float4*)(y3 + off + 4);
  float4 e0 = *(const float4*)(y4 + off), e1 = *(const float4*)(y4 + off + 4);
  s[0]=a0.x+b0.x+c0.x+d0.x+e0.x; s[1]=a0.y+b0.y+c0.y+d0.y+e0.y;
  s[2]=a0.z+b0.z+c0.z+d0.z+e0.z; s[3]=a0.w+b0.w+c0.w+d0.w+e0.w;
  s[4]=a1.x+b1.x+c1.x+d1.x+e1.x; s[5]=a1.y+b1.y+c1.y+d1.y+e1.y;
  s[6]=a1.z+b1.z+c1.z+d1.z+e1.z; s[7]=a1.w+b1.w+c1.w+d1.w+e1.w;
#pragma unroll
  for (int j = 0; j < 8; j++) ss += s[j] * s[j];
#pragma unroll
  for (int m = 1; m < 64; m <<= 1) ss += __shfl_xor(ss, m);
  __shared__ float sb[4];
  if ((tid & 63) == 0) sb[tid >> 6] = ss;
  __syncthreads();
  float rn = rsqrtf((sb[0] + sb[1] + sb[2] + sb[3]) * (1.f / 2048.f) + 1e-6f);
  float* xo = x1 + off;
  *(float4*)xo = *(float4*)&s[0];
  *(float4*)(xo + 4) = *(float4*)&s[4];
  const float* wr = w + c;
  float4 w0 = *(const float4*)wr, w1 = *(const float4*)(wr + 4);
  float wv[8] = {w0.x,w0.y,w0.z,w0.w,w1.x,w1.y,w1.z,w1.w};
  u16x8 r;
#pragma unroll
  for (int j = 0; j < 8; j++) r[j] = f2bf(s[j] * rn * wv[j]);
  *(u16x8*)(h2b + off) = r;
}

// ---------- bf16 GEMM: C[M,N] = A[M,K] * Bt[N,K]^T  (m97-style, strided) ----------
__global__ void __launch_bounds__(256) gemm_bt_kernel(const unsigned short* __restrict__ A,
                                                      const unsigned short* __restrict__ Bt,
                                                      float* __restrict__ C,
                                                      int M, int N, int K, int lda, int ldb) {
  __shared__ unsigned short As[128][32];
  __shared__ unsigned short Bs[128][32];
  const int tid = threadIdx.x;
  const int m0 = blockIdx.x << 7, n0 = blockIdx.y << 7;
  const int wave = tid >> 6, lane = tid & 63;
  const int wm = (wave >> 1) << 6, wn = (wave & 1) << 6;
  const int lrow = lane >> 2, lcol = lane & 3;
  const int ar0 = wave * 16 + lrow;
  const int ar1 = ar0 + 64;
  int br0 = n0 + ar0; br0 = br0 < N ? br0 : N - 1;
  int br1 = n0 + ar1; br1 = br1 < N ? br1 : N - 1;
  const unsigned short* Aptr0 = A + (size_t)(m0 + ar0) * lda + ((lcol ^ (ar0 & 3)) << 3);
  const unsigned short* Aptr1 = A + (size_t)(m0 + ar1) * lda + ((lcol ^ (ar1 & 3)) << 3);
  const unsigned short* Bptr0 = Bt + (size_t)br0 * ldb + ((lcol ^ (ar0 & 3)) << 3);
  const unsigned short* Bptr1 = Bt + (size_t)br1 * ldb + ((lcol ^ (ar1 & 3)) << 3);
  unsigned short* lA0 = &As[wave * 16][0];
  unsigned short* lA1 = &As[64 + wave * 16][0];
  unsigned short* lB0 = &Bs[wave * 16][0];
  unsigned short* lB1 = &Bs[64 + wave * 16][0];
  const int frow = lane & 15, fkb = lane >> 4;
  f32x4 acc[4][4];
#pragma unroll
  for (int i = 0; i < 4; i++)
#pragma unroll
    for (int j = 0; j < 4; j++) acc[i][j] = (f32x4){0.f, 0.f, 0.f, 0.f};

  for (int k0 = 0; k0 < K; k0 += 32) {
    gload16(Aptr0 + k0, lA0);
    gload16(Aptr1 + k0, lA1);
    gload16(Bptr0 + k0, lB0);
    gload16(Bptr1 + k0, lB1);
    __syncthreads();
    short8 af[4], bfr[4];
#pragma unroll
    for (int i = 0; i < 4; i++) {
      int ra = wm + i * 16 + frow;
      af[i] = *(const short8*)&As[ra][(fkb ^ (ra & 3)) << 3];
      int rb = wn + i * 16 + frow;
      bfr[i] = *(const short8*)&Bs[rb][(fkb ^ (rb & 3)) << 3];
    }
#pragma unroll
    for (int i = 0; i < 4; i++)
#pragma unroll
      for (int j = 0; j < 4; j++)
        acc[i][j] = __builtin_amdgcn_mfma_f32_16x16x32_bf16(af[i], bfr[j], acc[i][j], 0, 0, 0);
    __syncthreads();
  }
  const int crow = (lane >> 4) << 2, ccol = lane & 15;
#pragma unroll
  for (int i = 0; i < 4; i++) {
    const int gr = m0 + wm + i * 16 + crow;
#pragma unroll
    for (int j = 0; j < 4; j++) {
      const int gc = n0 + wn + j * 16 + ccol;
      if (gc < N) {
#pragma unroll
        for (int r = 0; r < 4; r++) C[(size_t)(gr + r) * N + gc] = acc[i][j][r];
      }
    }
  }
}

// ---------- split-K x4 GEMM in ONE launch: blockIdx.z picks K-quarter ----------
// 512 blocks -> 2 blocks/CU so the per-K-step barrier drain overlaps across
// co-resident blocks (m114 wave-level overlap).
__global__ void __launch_bounds__(256) gemm_bt_splitk4_kernel(const unsigned short* __restrict__ Abase,
                                                              const unsigned short* __restrict__ Btbase,
                                                              float* __restrict__ C0,
                                                              float* __restrict__ C1,
                                                              float* __restrict__ C2,
                                                              float* __restrict__ C3,
                                                              int M, int N, int Kq,
                                                              int lda, int ldb) {
  const unsigned short* A = Abase + (size_t)blockIdx.z * Kq;
  const unsigned short* Bt = Btbase + (size_t)blockIdx.z * Kq;
  float* C = (blockIdx.z == 0) ? C0 : (blockIdx.z == 1) ? C1 : (blockIdx.z == 2) ? C2 : C3;
  __shared__ unsigned short As[128][32];
  __shared__ unsigned short Bs[128][32];
  const int tid = threadIdx.x;
  const int m0 = blockIdx.x << 7, n0 = blockIdx.y << 7;
  const int wave = tid >> 6, lane = tid & 63;
  const int wm = (wave >> 1) << 6, wn = (wave & 1) << 6;
  const int lrow = lane >> 2, lcol = lane & 3;
  const int ar0 = wave * 16 + lrow;
  const int ar1 = ar0 + 64;
  int br0 = n0 + ar0; br0 = br0 < N ? br0 : N - 1;
  int br1 = n0 + ar1; br1 = br1 < N ? br1 : N - 1;
  const unsigned short* Aptr0 = A + (size_t)(m0 + ar0) * lda + ((lcol ^ (ar0 & 3)) << 3);
  const unsigned short* Aptr1 = A + (size_t)(m0 + ar1) * lda + ((lcol ^ (ar1 & 3)) << 3);
  const unsigned short* Bptr0 = Bt + (size_t)br0 * ldb + ((lcol ^ (ar0 & 3)) << 3);
  const unsigned short* Bptr1 = Bt + (size_t)br1 * ldb + ((lcol ^ (ar1 & 3)) << 3);
  unsigned short* lA0 = &As[wave * 16][0];
  unsigned short* lA1 = &As[64 + wave * 16][0];
  unsigned short* lB0 = &Bs[wave * 16][0];
  unsigned short* lB1 = &Bs[64 + wave * 16][0];
  const int frow = lane & 15, fkb = lane >> 4;
  f32x4 acc[4][4];
#pragma unroll
  for (int i = 0; i < 4; i++)
#pragma unroll
    for (int j = 0; j < 4; j++) acc[i][j] = (f32x4){0.f, 0.f, 0.f, 0.f};

  for (int k0 = 0; k0 < Kq; k0 += 32) {
    gload16(Aptr0 + k0, lA0);
    gload16(Aptr1 + k0, lA1);
    gload16(Bptr0 + k0, lB0);
    gload16(Bptr1 + k0, lB1);
    __syncthreads();
    short8 af[4], bfr[4];
#pragma unroll
    for (int i = 0; i < 4; i++) {
      int ra = wm + i * 16 + frow;
      af[i] = *(const short8*)&As[ra][(fkb ^ (ra & 3)) << 3];
      int rb = wn + i * 16 + frow;
      bfr[i] = *(const short8*)&Bs[rb][(fkb ^ (rb & 3)) << 3];
    }
#pragma unroll
    for (int i = 0; i < 4; i++)
#pragma unroll
      for (int j = 0; j < 4; j++)
        acc[i][j] = __builtin_amdgcn_mfma_f32_16x16x32_bf16(af[i], bfr[j], acc[i][j], 0, 0, 0);
    __syncthreads();
  }
  const int crow = (lane >> 4) << 2, ccol = lane & 15;
#pragma unroll
  for (int i = 0; i < 4; i++) {
    const int gr = m0 + wm + i * 16 + crow;
#pragma unroll
    for (int j = 0; j < 4; j++) {
      const int gc = n0 + wn + j * 16 + ccol;
      if (gc < N) {
#pragma unroll
        for (int r = 0; r < 4; r++) C[(size_t)(gr + r) * N + gc] = acc[i][j][r];
      }
    }
  }
}

// ---------- fused MLP1: mid = bf16(silu(A*B1t^T) * (A*B2t^T)), N=8192, K=2048 ----------
__global__ void __launch_bounds__(256) gemm_dual_swiglu_kernel(const unsigned short* __restrict__ A,
                                                               const unsigned short* __restrict__ Bt,
                                                               unsigned short* __restrict__ mid) {
  __shared__ unsigned short As[128][32];
  __shared__ unsigned short B1s[128][32];
  __shared__ unsigned short B2s[128][32];
  const int tid = threadIdx.x;
  const int m0 = blockIdx.x << 7, n0 = blockIdx.y << 7;
  const int wave = tid >> 6, lane = tid & 63;
  const int wm = (wave >> 1) << 6, wn = (wave & 1) << 6;
  const int lrow = lane >> 2, lcol = lane & 3;
  const int ar0 = wave * 16 + lrow;
  const int ar1 = ar0 + 64;
  const unsigned short* Aptr0 = A + (size_t)(m0 + ar0) * 2048 + ((lcol ^ (ar0 & 3)) << 3);
  const unsigned short* Aptr1 = A + (size_t)(m0 + ar1) * 2048 + ((lcol ^ (ar1 & 3)) << 3);
  const unsigned short* B1p0 = Bt + (size_t)(n0 + ar0) * 2048 + ((lcol ^ (ar0 & 3)) << 3);
  const unsigned short* B1p1 = Bt + (size_t)(n0 + ar1) * 2048 + ((lcol ^ (ar1 & 3)) << 3);
  const unsigned short* B2p0 = B1p0 + (size_t)8192 * 2048;
  const unsigned short* B2p1 = B1p1 + (size_t)8192 * 2048;
  unsigned short* lA0 = &As[wave * 16][0];
  unsigned short* lA1 = &As[64 + wave * 16][0];
  unsigned short* lB10 = &B1s[wave * 16][0];
  unsigned short* lB11 = &B1s[64 + wave * 16][0];
  unsigned short* lB20 = &B2s[wave * 16][0];
  unsigned short* lB21 = &B2s[64 + wave * 16][0];
  const int frow = lane & 15, fkb = lane >> 4;
  f32x4 acc1[4][4], acc2[4][4];
#pragma unroll
  for (int i = 0; i < 4; i++)
#pragma unroll
    for (int j = 0; j < 4; j++) {
      acc1[i][j] = (f32x4){0.f, 0.f, 0.f, 0.f};
      acc2[i][j] = (f32x4){0.f, 0.f, 0.f, 0.f};
    }
  for (int k0 = 0; k0 < 2048; k0 += 32) {
    gload16(Aptr0 + k0, lA0);
    gload16(Aptr1 + k0, lA1);
    gload16(B1p0 + k0, lB10);
    gload16(B1p1 + k0, lB11);
    gload16(B2p0 + k0, lB20);
    gload16(B2p1 + k0, lB21);
    __syncthreads();
    short8 af[4], b1f[4], b2f[4];
#pragma unroll
    for (int i = 0; i < 4; i++) {
      int ra = wm + i * 16 + frow;
      af[i] = *(const short8*)&As[ra][(fkb ^ (ra & 3)) << 3];
      int rb = wn + i * 16 + frow;
      b1f[i] = *(const short8*)&B1s[rb][(fkb ^ (rb & 3)) << 3];
      b2f[i] = *(const short8*)&B2s[rb][(fkb ^ (rb & 3)) << 3];
    }
#pragma unroll
    for (int i = 0; i < 4; i++)
#pragma unroll
      for (int j = 0; j < 4; j++) {
        acc1[i][j] = __builtin_amdgcn_mfma_f32_16x16x32_bf16(af[i], b1f[j], acc1[i][j], 0, 0, 0);
        acc2[i][j] = __builtin_amdgcn_mfma_f32_16x16x32_bf16(af[i], b2f[j], acc2[i][j], 0, 0, 0);
      }
    __syncthreads();
  }
  const int crow = (lane >> 4) << 2, ccol = lane & 15;
#pragma unroll
  for (int i = 0; i < 4; i++) {
    const int gr = m0 + wm + i * 16 + crow;
#pragma unroll
    for (int j = 0; j < 4; j++) {
      const int gc = n0 + wn + j * 16 + ccol;
#pragma unroll
      for (int r = 0; r < 4; r++)
        mid[(size_t)(gr + r) * 8192 + gc] = f2bf(silu_f(acc1[i][j][r]) * acc2[i][j][r]);
    }
  }
}

// ---------- MERGED: causal dwconv + silu + l2norm + qk dot + gates ----------
__global__ void __launch_bounds__(256) conv_gates_kernel(const float* __restrict__ proj,
                                                         const float* __restrict__ cq,
                                                         const float* __restrict__ ck,
                                                         const float* __restrict__ cv,
                                                         const float* __restrict__ small,
                                                         const float* __restrict__ wfb,
                                                         const float* __restrict__ a_log,
                                                         const float* __restrict__ dtb,
                                                         float* __restrict__ q, float* __restrict__ k,
                                                         float* __restrict__ v,
                                                         float4* __restrict__ g4,
                                                         unsigned short* __restrict__ gab) {
  __shared__ float qksh[16];
  const int t = blockIdx.x, tid = threadIdx.x;
  const int c = tid << 3;
  float aq[8] = {0,0,0,0,0,0,0,0}, ak[8] = {0,0,0,0,0,0,0,0}, av[8] = {0,0,0,0,0,0,0,0};
#pragma unroll
  for (int i = 0; i < 4; i++) {
    const int tt = t + i - 3;
    if (tt < 0) continue;
    const float* pr = proj + (size_t)tt * 6144;
    float pq[8], pk[8], pv[8], w0[8], w1[8], w2[8];
    *(float4*)&pq[0] = *(const float4*)(pr + c);        *(float4*)&pq[4] = *(const float4*)(pr + c + 4);
    *(float4*)&pk[0] = *(const float4*)(pr + 2048 + c); *(float4*)&pk[4] = *(const float4*)(pr + 2048 + c + 4);
    *(float4*)&pv[0] = *(const float4*)(pr + 4096 + c); *(float4*)&pv[4] = *(const float4*)(pr + 4096 + c + 4);
    *(float4*)&w0[0] = *(const float4*)(cq + i * 2048 + c); *(float4*)&w0[4] = *(const float4*)(cq + i * 2048 + c + 4);
    *(float4*)&w1[0] = *(const float4*)(ck + i * 2048 + c); *(float4*)&w1[4] = *(const float4*)(ck + i * 2048 + c + 4);
    *(float4*)&w2[0] = *(const float4*)(cv + i * 2048 + c); *(float4*)&w2[4] = *(const float4*)(cv + i * 2048 + c + 4);
#pragma unroll
    for (int j = 0; j < 8; j++) { aq[j] += w0[j]*pq[j]; ak[j] += w1[j]*pk[j]; av[j] += w2[j]*pv[j]; }
  }
  float sq[8], sk[8], sv[8]; float ssq = 0.f, ssk = 0.f;
#pragma unroll
  for (int j = 0; j < 8; j++) {
    sq[j] = silu_f(aq[j]); ssq += sq[j]*sq[j];
    sk[j] = silu_f(ak[j]); ssk += sk[j]*sk[j];
    sv[j] = silu_f(av[j]);
  }
  ssq = red16(ssq); ssk = red16(ssk);
  const float rq = rsqrtf(ssq + 1e-6f) * 0.08838834764831845f;  // * DK^-0.5
  const float rk = rsqrtf(ssk + 1e-6f);
  float oq[8], ok[8]; float qkl = 0.f;
#pragma unroll
  for (int j = 0; j < 8; j++) { oq[j] = sq[j]*rq; ok[j] = sk[j]*rk; qkl += oq[j]*ok[j]; }
  qkl = red16(qkl);
  if ((tid & 15) == 0) qksh[tid >> 4] = qkl;
  float* qo = q + (size_t)t * 2048 + c;
  *(float4*)qo = *(float4*)&oq[0]; *(float4*)(qo + 4) = *(float4*)&oq[4];
  float* ko = k + (size_t)t * 2048 + c;
  *(float4*)ko = *(float4*)&ok[0]; *(float4*)(ko + 4) = *(float4*)&ok[4];
  float* vo = v + (size_t)t * 2048 + c;
  *(float4*)vo = *(float4*)&sv[0]; *(float4*)(vo + 4) = *(float4*)&sv[4];
  __syncthreads();
  if (tid < 128) {
    const float* srow = small + (size_t)t * 272;
    const int hh = tid >> 3, j = tid & 7;
    float d = 0.f;
#pragma unroll
    for (int i = 0; i < 16; i++) d += srow[j * 16 + i] * wfb[(j * 16 + i) * 16 + hh];
    d += __shfl_xor(d, 1); d += __shfl_xor(d, 2); d += __shfl_xor(d, 4);
    if (j == 0) {
      d += dtb[hh];
      float sp = (d > 20.f) ? d : log1pf(expf(d));
      float eg = expf(-expf(a_log[hh]) * sp);
      float bt = 1.f / (1.f + expf(-srow[128 + hh]));
      g4[t * 16 + hh] = make_float4(eg, bt, qksh[hh], 0.f);
    }
    gab[(size_t)t * 128 + tid] = f2bf(srow[144 + tid]);
  }
}

// ---------- gated delta-rule scan (known-good: 8x20-reg slots) ----------
struct Slot { float4 k0, k1, q0, q1; float eg, qk, btv, bteg; };

__device__ __forceinline__ void load_slot(Slot& X, const float* kb, const float* qb,
                                          const float* vb, const float4* g4b, int tt) {
  const float* kp = kb + (size_t)tt * 2048;
  const float* qp = qb + (size_t)tt * 2048;
  X.k0 = *(const float4*)kp; X.k1 = *(const float4*)(kp + 4);
  X.q0 = *(const float4*)qp; X.q1 = *(const float4*)(qp + 4);
  float4 g = g4b[(size_t)tt * 16];
  float v = vb[(size_t)tt * 2048];
  X.eg = g.x; X.qk = g.z;
  X.btv = g.y * v;            // off-chain precompute
  X.bteg = g.y * g.x;
}

__device__ __forceinline__ void step_slot(const Slot& X, float (&S)[8], float* ob,
                                          bool dostore, int tt) {
  float a0 = fmaf(X.k1.x, S[4], X.k0.x * S[0]);
  float a1 = fmaf(X.k1.y, S[5], X.k0.y * S[1]);
  float a2 = fmaf(X.k1.z, S[6], X.k0.z * S[2]);
  float a3 = fmaf(X.k1.w, S[7], X.k0.w * S[3]);
  float b0 = fmaf(X.q1.x, S[4], X.q0.x * S[0]);
  float b1 = fmaf(X.q1.y, S[5], X.q0.y * S[1]);
  float b2 = fmaf(X.q1.z, S[6], X.q0.z * S[2]);
  float b3 = fmaf(X.q1.w, S[7], X.q0.w * S[3]);
  float kS = red16d((a0 + a1) + (a2 + a3));
  float qS = red16d((b0 + b1) + (b2 + b3));
  float delta = fmaf(-X.bteg, kS, X.btv);   // bt*(v - eg*kS)
  S[0] = fmaf(X.k0.x, delta, X.eg * S[0]);
  S[1] = fmaf(X.k0.y, delta, X.eg * S[1]);
  S[2] = fmaf(X.k0.z, delta, X.eg * S[2]);
  S[3] = fmaf(X.k0.w, delta, X.eg * S[3]);
  S[4] = fmaf(X.k1.x, delta, X.eg * S[4]);
  S[5] = fmaf(X.k1.y, delta, X.eg * S[5]);
  S[6] = fmaf(X.k1.z, delta, X.eg * S[6]);
  S[7] = fmaf(X.k1.w, delta, X.eg * S[7]);
  if (dostore) ob[(size_t)tt * 2048] = fmaf(X.qk, delta, X.eg * qS);
}

__global__ void __launch_bounds__(64, 1) scan_kernel(const float* __restrict__ q,
                                                     const float* __restrict__ k,
                                                     const float* __restrict__ v,
                                                     const float4* __restrict__ g4,
                                                     float* __restrict__ o) {
  // XCD swizzle: b&7 = XCD -> heads 2x,2x+1 stay on one XCD
  const int b = blockIdx.x;            // 512 = 16 heads * 32 slices
  const int xcd = b & 7, r = b >> 3;
  const int h = (xcd << 1) | (r >> 5);
  const int vbase = (r & 31) << 2;
  const int lane = threadIdx.x;
  const int kl = lane & 15, vl = lane >> 4;
  const int vcol = vbase + vl;
  const int koff = h * 128 + kl * 8;
  const int voff = h * 128 + vcol;
  const float* kb = k + koff;
  const float* qb = q + koff;
  const float* vb = v + voff;
  const float4* g4b = g4 + h;
  float* ob = o + voff;
  const bool dostore = (kl == 0);
  float S[8] = {0,0,0,0,0,0,0,0};
  Slot s0, s1, s2, s3, s4, s5, s6, s7;
  load_slot(s0, kb, qb, vb, g4b, 0);
  load_slot(s1, kb, qb, vb, g4b, 1);
  load_slot(s2, kb, qb, vb, g4b, 2);
  load_slot(s3, kb, qb, vb, g4b, 3);
  load_slot(s4, kb, qb, vb, g4b, 4);
  load_slot(s5, kb, qb, vb, g4b, 5);
  load_slot(s6, kb, qb, vb, g4b, 6);
  load_slot(s7, kb, qb, vb, g4b, 7);
  // prefetch reads past t=1023 land in adjacent ws regions (in-bounds, unconsumed)
  for (int t = 0; t < 1024; t += 8) {
    step_slot(s0, S, ob, dostore, t + 0); load_slot(s0, kb, qb, vb, g4b, t + 8);
    step_slot(s1, S, ob, dostore, t + 1); load_slot(s1, kb, qb, vb, g4b, t + 9);
    step_slot(s2, S, ob, dostore, t + 2); load_slot(s2, kb, qb, vb, g4b, t + 10);
    step_slot(s3, S, ob, dostore, t + 3); load_slot(s3, kb, qb, vb, g4b, t + 11);
    step_slot(s4, S, ob, dostore, t + 4); load_slot(s4, kb, qb, vb, g4b, t + 12);
    step_slot(s5, S, ob, dostore, t + 5); load_slot(s5, kb, qb, vb, g4b, t + 13);
    step_slot(s6, S, ob, dostore, t + 6); load_slot(s6, kb, qb, vb, g4b, t + 14);
    step_slot(s7, S, ob, dostore, t + 7); load_slot(s7, kb, qb, vb, g4b, t + 15);
  }
}

// ---------- o_gated = bf16(rmsnorm_head(o)*w * silu(gate)) ----------
__global__ void __launch_bounds__(256) gate_o_kernel(const float* __restrict__ o,
                                                     const float* __restrict__ gate,
                                                     const float* __restrict__ onw,
                                                     unsigned short* __restrict__ ogb) {
  const int t = blockIdx.x, tid = threadIdx.x;
  const int c = tid << 3;
  const float* orow = o + (size_t)t * 2048 + c;
  float ov[8]; *(float4*)&ov[0] = *(const float4*)orow; *(float4*)&ov[4] = *(const float4*)(orow + 4);
  float ss = 0.f;
#pragma unroll
  for (int j = 0; j < 8; j++) ss += ov[j] * ov[j];
  ss = red16(ss);
  const float rn = rsqrtf(ss * (1.f / 128.f) + 1e-6f);
  const int dv = (tid & 15) << 3;
  float wv[8]; *(float4*)&wv[0] = *(const float4*)(onw + dv); *(float4*)&wv[4] = *(const float4*)(onw + dv + 4);
  const float* grow = gate + (size_t)t * 2048 + c;
  float gv[8]; *(float4*)&gv[0] = *(const float4*)grow; *(float4*)&gv[4] = *(const float4*)(grow + 4);
  u16x8 r;
#pragma unroll
  for (int j = 0; j < 8; j++) r[j] = f2bf(ov[j] * rn * wv[j] * silu_f(gv[j]));
  *(u16x8*)(ogb + (size_t)t * 2048 + c) = r;
}

// ---------- out = a + p0+p1+p2+p3 ----------
__global__ void final_add5_kernel(const float* __restrict__ a, const float* __restrict__ p0,
                                  const float* __restrict__ p1, const float* __restrict__ p2,
                                  const float* __restrict__ p3, float* __restrict__ out) {
  const int NU = 1024 * 512;
  for (int u = blockIdx.x * blockDim.x + threadIdx.x; u < NU; u += gridDim.x * blockDim.x) {
    float4 va = ((const float4*)a)[u];
    float4 v0 = ((const float4*)p0)[u];
    float4 v1 = ((const float4*)p1)[u];
    float4 v2 = ((const float4*)p2)[u];
    float4 v3 = ((const float4*)p3)[u];
    va.x += v0.x + v1.x + v2.x + v3.x;
    va.y += v0.y + v1.y + v2.y + v3.y;
    va.z += v0.z + v1.z + v2.z + v3.z;
    va.w += v0.w + v1.w + v2.w + v3.w;
    ((float4*)out)[u] = va;
  }
}

// ---------- ws layout (bytes) ----------
constexpr size_t SZ_WQKVT   = (size_t)6144 * 2048 * 2;
constexpr size_t SZ_WSMALLT = (size_t)272 * 2048 * 2;
constexpr size_t SZ_WGBT    = (size_t)2048 * 128 * 2;
constexpr size_t SZ_WOT     = (size_t)2048 * 2048 * 2;
constexpr size_t SZ_WMLP1T  = (size_t)16384 * 2048 * 2;
constexpr size_t SZ_WDOWNT  = (size_t)2048 * 8192 * 2;
constexpr size_t OFF_WQKVT   = 0;
constexpr size_t OFF_WSMALLT = OFF_WQKVT + SZ_WQKVT;
constexpr size_t OFF_WGBT    = OFF_WSMALLT + SZ_WSMALLT;
constexpr size_t OFF_WOT     = OFF_WGBT + SZ_WGBT;
constexpr size_t OFF_WMLP1T  = OFF_WOT + SZ_WOT;
constexpr size_t OFF_WDOWNT  = OFF_WMLP1T + SZ_WMLP1T;
constexpr size_t A0          = OFF_WDOWNT + SZ_WDOWNT;
constexpr size_t OFF_HB    = A0;
constexpr size_t OFF_PROJ  = OFF_HB + (size_t)1024 * 2048 * 2;
constexpr size_t OFF_SMALL = OFF_PROJ + (size_t)1024 * 6144 * 4;
constexpr size_t OFF_Q     = OFF_SMALL + (size_t)1024 * 272 * 4;
constexpr size_t OFF_K     = OFF_Q + (size_t)1024 * 2048 * 4;
constexpr size_t OFF_V     = OFF_K + (size_t)1024 * 2048 * 4;
constexpr size_t OFF_G     = OFF_V + (size_t)1024 * 2048 * 4;   // scan over-read pad
constexpr size_t OFF_BETA  = OFF_G + (size_t)1024 * 16 * 4;
constexpr size_t OFF_GAB   = OFF_BETA + (size_t)1024 * 16 * 4;
constexpr size_t OFF_GATE  = OFF_GAB + (size_t)1024 * 128 * 2;
constexpr size_t OFF_O     = OFF_GATE + (size_t)1024 * 2048 * 4;
constexpr size_t OFF_OGB   = OFF_O + (size_t)1024 * 2048 * 4;
constexpr size_t OFF_OPROJ = OFF_OGB + (size_t)1024 * 2048 * 2;
constexpr size_t OFF_X1    = OFF_OPROJ + (size_t)1024 * 2048 * 4;
constexpr size_t OFF_H2B   = OFF_X1 + (size_t)1024 * 2048 * 4;
constexpr size_t OFF_MID    = A0 + (size_t)1024 * 16384 * 4;   // overlaps dead GATE/O/OGB/OPROJ only
constexpr size_t OFF_MLPOUT = OFF_H2B + (size_t)1024 * 2048 * 2;
constexpr size_t OFF_QKB    = OFF_MLPOUT + (size_t)1024 * 2048 * 4;   // (layout keep)
constexpr size_t OFF_G4     = OFF_QKB + (size_t)1024 * 16 * 4;        // [1040][16] float4 (tail pad)
constexpr size_t OFF_MLPOUT2= OFF_G4 + (size_t)1040 * 16 * 16;
constexpr size_t WS_NEED    = OFF_MLPOUT2 + (size_t)1024 * 2048 * 4;
// liveness aliases for the extra split-K partials:
constexpr size_t OFF_OPROJ2 = OFF_O;                                  // dead `of` after gate_o
constexpr size_t OFF_OPROJ3 = OFF_PROJ;                               // dead projf after conv_gates
constexpr size_t OFF_OPROJ4 = OFF_PROJ + (size_t)1024 * 2048 * 4;
constexpr size_t OFF_MLPOUT3 = OFF_Q;                                 // dead qf after scan
constexpr size_t OFF_MLPOUT4 = OFF_K;                                 // dead kf after scan

extern "C" void kernel_launch(void* const* d_in, const int* in_sizes, int n_in,
                              void* d_out, int out_size, void* d_ws, size_t ws_size,
                              hipStream_t stream) {
  (void)in_sizes; (void)n_in; (void)out_size;
  const float* x     = (const float*)d_in[0];
  const float* wq    = (const float*)d_in[1];
  const float* wk    = (const float*)d_in[2];
  const float* wv    = (const float*)d_in[3];
  const float* cq    = (const float*)d_in[4];
  const float* ck    = (const float*)d_in[5];
  const float* cv    = (const float*)d_in[6];
  const float* wfa   = (const float*)d_in[7];
  const float* wfb   = (const float*)d_in[8];
  const float* wb    = (const float*)d_in[9];
  const float* wga   = (const float*)d_in[10];
  const float* wgb   = (const float*)d_in[11];
  const float* a_log = (const float*)d_in[12];
  const float* dtb   = (const float*)d_in[13];
  const float* onw   = (const float*)d_in[14];
  const float* wo    = (const float*)d_in[15];
  const float* ln1   = (const float*)d_in[16];
  const float* ln2   = (const float*)d_in[17];
  const float* wgate = (const float*)d_in[18];
  const float* wup   = (const float*)d_in[19];
  const float* wdown = (const float*)d_in[20];
  float* out = (float*)d_out;
  char* ws = (char*)d_ws;
  if (ws_size < WS_NEED) return;

  unsigned short* wqkvT   = (unsigned short*)(ws + OFF_WQKVT);
  unsigned short* wsmallT = (unsigned short*)(ws + OFF_WSMALLT);
  unsigned short* wgbT    = (unsigned short*)(ws + OFF_WGBT);
  unsigned short* woT     = (unsigned short*)(ws + OFF_WOT);
  unsigned short* wmlp1T  = (unsigned short*)(ws + OFF_WMLP1T);
  unsigned short* wdownT  = (unsigned short*)(ws + OFF_WDOWNT);
  unsigned short* hb      = (unsigned short*)(ws + OFF_HB);
  float* projf  = (float*)(ws + OFF_PROJ);
  float* smallf = (float*)(ws + OFF_SMALL);
  float* qf     = (float*)(ws + OFF_Q);
  float* kf     = (float*)(ws + OFF_K);
  float* vf     = (float*)(ws + OFF_V);
  unsigned short* gab = (unsigned short*)(ws + OFF_GAB);
  float* gatef  = (float*)(ws + OFF_GATE);
  float* of     = (float*)(ws + OFF_O);
  unsigned short* ogb = (unsigned short*)(ws + OFF_OGB);
  float* oprojf = (float*)(ws + OFF_OPROJ);
  float* oproj2f= (float*)(ws + OFF_OPROJ2);
  float* oproj3f= (float*)(ws + OFF_OPROJ3);
  float* oproj4f= (float*)(ws + OFF_OPROJ4);
  float* x1f    = (float*)(ws + OFF_X1);
  unsigned short* h2b = (unsigned short*)(ws + OFF_H2B);
  unsigned short* midb = (unsigned short*)(ws + OFF_MID);
  float* mlpoutf  = (float*)(ws + OFF_MLPOUT);
  float* mlpout2f = (float*)(ws + OFF_MLPOUT2);
  float* mlpout3f = (float*)(ws + OFF_MLPOUT3);
  float* mlpout4f = (float*)(ws + OFF_MLPOUT4);
  float4* g4    = (float4*)(ws + OFF_G4);

  // --- one transpose launch for all 11 weights ---
  TDescs tds;
  int st = 0;
  auto set = [&](int i, const float* s, unsigned short* d, int R, int C) {
    int tx = (C + 63) / 64, ty = (R + 63) / 64;
    tds.d[i] = TDesc{s, d, R, C, tx, st};
    st += tx * ty;
  };
  set(0, wq, wqkvT, 2048, 2048);
  set(1, wk, wqkvT + (size_t)2048 * 2048, 2048, 2048);
  set(2, wv, wqkvT + (size_t)4096 * 2048, 2048, 2048);
  set(3, wfa, wsmallT, 2048, 128);
  set(4, wb, wsmallT + (size_t)128 * 2048, 2048, 16);
  set(5, wga, wsmallT + (size_t)144 * 2048, 2048, 128);
  set(6, wgb, wgbT, 128, 2048);
  set(7, wo, woT, 2048, 2048);
  set(8, wgate, wmlp1T, 2048, 8192);
  set(9, wup, wmlp1T + (size_t)8192 * 2048, 2048, 8192);
  set(10, wdown, wdownT, 8192, 2048);
  trans_all_kernel<<<st, 256, 0, stream>>>(tds);

  rmsnorm_bf16_kernel<<<1024, 256, 0, stream>>>(x, ln1, hb);
  gemm_bt_kernel<<<dim3(8, 48), 256, 0, stream>>>(hb, wqkvT, projf, 1024, 6144, 2048, 2048, 2048);
  gemm_bt_kernel<<<dim3(8, 3), 256, 0, stream>>>(hb, wsmallT, smallf, 1024, 272, 2048, 2048, 2048);
  conv_gates_kernel<<<1024, 256, 0, stream>>>(projf, cq, ck, cv, smallf, wfb, a_log, dtb,
                                              qf, kf, vf, g4, gab);
  gemm_bt_kernel<<<dim3(8, 16), 256, 0, stream>>>(gab, wgbT, gatef, 1024, 2048, 128, 128, 128);
  scan_kernel<<<512, 64, 0, stream>>>(qf, kf, vf, g4, of);
  gate_o_kernel<<<1024, 256, 0, stream>>>(of, gatef, onw, ogb);
  // wo: split-K x4 in ONE launch (512 blocks, 2/CU)
  gemm_bt_splitk4_kernel<<<dim3(8, 16, 4), 256, 0, stream>>>(ogb, woT,
      oprojf, oproj2f, oproj3f, oproj4f, 1024, 2048, 512, 2048, 2048);
  add5_rmsnorm_kernel<<<1024, 256, 0, stream>>>(x, oprojf, oproj2f, oproj3f, oproj4f,
                                                ln2, x1f, h2b);
  gemm_dual_swiglu_kernel<<<dim3(8, 64), 256, 0, stream>>>(h2b, wmlp1T, midb);
  // down-proj: split-K x4 in ONE launch (512 blocks, 2/CU)
  gemm_bt_splitk4_kernel<<<dim3(8, 16, 4), 256, 0, stream>>>(midb, wdownT,
      mlpoutf, mlpout2f, mlpout3f, mlpout4f, 1024, 2048, 2048, 8192, 8192);
  final_add5_kernel<<<2048, 256, 0, stream>>>(x1f, mlpoutf, mlpout2f, mlpout3f, mlpout4f, out);
}

// Round 14
// 623.710 us; speedup vs baseline: 1.3634x; 1.1207x over previous
//
#include <hip/hip_runtime.h>
#include <hip/hip_bf16.h>

typedef __attribute__((ext_vector_type(8))) short short8;
typedef __attribute__((ext_vector_type(4))) float f32x4;
typedef __attribute__((ext_vector_type(8))) unsigned short u16x8;
typedef __attribute__((ext_vector_type(4))) unsigned short u16x4;

// ---------- helpers ----------
__device__ __forceinline__ unsigned short f2bf(float f) {
  unsigned u = __float_as_uint(f);
  u += 0x7fffu + ((u >> 16) & 1u);          // round-to-nearest-even
  return (unsigned short)(u >> 16);
}
__device__ __forceinline__ float silu_f(float x) { return x / (1.f + __expf(-x)); }
__device__ __forceinline__ float red16(float v) {
  v += __shfl_xor(v, 1); v += __shfl_xor(v, 2);
  v += __shfl_xor(v, 4); v += __shfl_xor(v, 8);
  return v;
}
template <int CTRL>
__device__ __forceinline__ float dpp_mv(float v) {
  return __int_as_float(__builtin_amdgcn_update_dpp(0, __float_as_int(v), CTRL, 0xF, 0xF, true));
}
__device__ __forceinline__ float red16d(float v) {
  v += dpp_mv<0xB1>(v);   // quad_perm [1,0,3,2]
  v += dpp_mv<0x4E>(v);   // quad_perm [2,3,0,1]
  v += dpp_mv<0x141>(v);  // row_half_mirror
  v += dpp_mv<0x140>(v);  // row_mirror
  return v;
}
__device__ __forceinline__ void gload16(const void* g, void* l) {
  __builtin_amdgcn_global_load_lds((const __attribute__((address_space(1))) void*)g,
                                   (__attribute__((address_space(3))) void*)l, 16, 0, 0);
}

// ---------- EARLY weight transposes (qkv/small/gb) in ONE launch ----------
struct TDesc { const float* src; unsigned short* dst; int R, C, tilesX, start; };
struct TDescs { TDesc d[7]; };

__global__ void __launch_bounds__(256) trans_early_kernel(TDescs ds) {
  __shared__ float tile[64][65];   // tile[col'][row']
  const int bid = blockIdx.x;
  int e = 0;
#pragma unroll
  for (int i = 1; i < 7; i++) e = (bid >= ds.d[i].start) ? i : e;
  const float* __restrict__ src = ds.d[e].src;
  unsigned short* __restrict__ dst = ds.d[e].dst;
  const int R = ds.d[e].R, C = ds.d[e].C;
  const int local = bid - ds.d[e].start;
  const int c0 = (local % ds.d[e].tilesX) * 64;
  const int r0 = (local / ds.d[e].tilesX) * 64;
  const int tid = threadIdx.x;
  const int l = tid & 15, g = tid >> 4;
#pragma unroll
  for (int i = 0; i < 4; i++) {
    const int r = r0 + g + 16 * i;
    const int c = c0 + 4 * l;
    if (r < R) {
      if (c + 3 < C) {
        float4 v = *(const float4*)(src + (size_t)r * C + c);
        tile[4 * l + 0][g + 16 * i] = v.x;
        tile[4 * l + 1][g + 16 * i] = v.y;
        tile[4 * l + 2][g + 16 * i] = v.z;
        tile[4 * l + 3][g + 16 * i] = v.w;
      } else {
#pragma unroll
        for (int j = 0; j < 4; j++)
          if (c + j < C) tile[4 * l + j][g + 16 * i] = src[(size_t)r * C + c + j];
      }
    }
  }
  __syncthreads();
#pragma unroll
  for (int i = 0; i < 4; i++) {
    const int cc = c0 + g + 16 * i;
    const int rc = r0 + 4 * l;
    if (cc < C) {
      if (rc + 3 < R) {
        u16x4 o;
        o[0] = f2bf(tile[g + 16 * i][4 * l + 0]);
        o[1] = f2bf(tile[g + 16 * i][4 * l + 1]);
        o[2] = f2bf(tile[g + 16 * i][4 * l + 2]);
        o[3] = f2bf(tile[g + 16 * i][4 * l + 3]);
        *(u16x4*)(dst + (size_t)cc * R + rc) = o;
      } else {
#pragma unroll
        for (int j = 0; j < 4; j++)
          if (rc + j < R) dst[(size_t)cc * R + rc + j] = f2bf(tile[g + 16 * i][4 * l + j]);
      }
    }
  }
}

// ---------- rmsnorm (D=2048) -> bf16 ----------
__global__ void __launch_bounds__(256) rmsnorm_bf16_kernel(const float* __restrict__ x,
                                                           const float* __restrict__ w,
                                                           unsigned short* __restrict__ outb) {
  const int t = blockIdx.x, tid = threadIdx.x;
  const float* xr = x + (size_t)t * 2048 + tid * 8;
  float4 v0 = *(const float4*)xr, v1 = *(const float4*)(xr + 4);
  float ss = v0.x*v0.x + v0.y*v0.y + v0.z*v0.z + v0.w*v0.w
           + v1.x*v1.x + v1.y*v1.y + v1.z*v1.z + v1.w*v1.w;
#pragma unroll
  for (int m = 1; m < 64; m <<= 1) ss += __shfl_xor(ss, m);
  __shared__ float sb[4];
  if ((tid & 63) == 0) sb[tid >> 6] = ss;
  __syncthreads();
  float rn = rsqrtf((sb[0] + sb[1] + sb[2] + sb[3]) * (1.f / 2048.f) + 1e-6f);
  const float* wr = w + tid * 8;
  float4 w0 = *(const float4*)wr, w1 = *(const float4*)(wr + 4);
  u16x8 r;
  r[0]=f2bf(v0.x*rn*w0.x); r[1]=f2bf(v0.y*rn*w0.y); r[2]=f2bf(v0.z*rn*w0.z); r[3]=f2bf(v0.w*rn*w0.w);
  r[4]=f2bf(v1.x*rn*w1.x); r[5]=f2bf(v1.y*rn*w1.y); r[6]=f2bf(v1.z*rn*w1.z); r[7]=f2bf(v1.w*rn*w1.w);
  *(u16x8*)(outb + (size_t)t * 2048 + tid * 8) = r;
}

// ---------- x1 = x + y1..y4 ; h2b = bf16(rmsnorm(x1)*w) ----------
__global__ void __launch_bounds__(256) add5_rmsnorm_kernel(const float* __restrict__ x,
                                                           const float* __restrict__ y1,
                                                           const float* __restrict__ y2,
                                                           const float* __restrict__ y3,
                                                           const float* __restrict__ y4,
                                                           const float* __restrict__ w,
                                                           float* __restrict__ x1,
                                                           unsigned short* __restrict__ h2b) {
  const int t = blockIdx.x, tid = threadIdx.x;
  const int c = tid * 8;
  const size_t off = (size_t)t * 2048 + c;
  float s[8]; float ss = 0.f;
  float4 a0 = *(const float4*)(x + off),  a1 = *(const float4*)(x + off + 4);
  float4 b0 = *(const float4*)(y1 + off), b1 = *(const float4*)(y1 + off + 4);
  float4 c0 = *(const float4*)(y2 + off), c1 = *(const float4*)(y2 + off + 4);
  float4 d0 = *(const float4*)(y3 + off), d1 = *(const float4*)(y3 + off + 4);
  float4 e0 = *(const float4*)(y4 + off), e1 = *(const float4*)(y4 + off + 4);
  s[0]=a0.x+b0.x+c0.x+d0.x+e0.x; s[1]=a0.y+b0.y+c0.y+d0.y+e0.y;
  s[2]=a0.z+b0.z+c0.z+d0.z+e0.z; s[3]=a0.w+b0.w+c0.w+d0.w+e0.w;
  s[4]=a1.x+b1.x+c1.x+d1.x+e1.x; s[5]=a1.y+b1.y+c1.y+d1.y+e1.y;
  s[6]=a1.z+b1.z+c1.z+d1.z+e1.z; s[7]=a1.w+b1.w+c1.w+d1.w+e1.w;
#pragma unroll
  for (int j = 0; j < 8; j++) ss += s[j] * s[j];
#pragma unroll
  for (int m = 1; m < 64; m <<= 1) ss += __shfl_xor(ss, m);
  __shared__ float sb[4];
  if ((tid & 63) == 0) sb[tid >> 6] = ss;
  __syncthreads();
  float rn = rsqrtf((sb[0] + sb[1] + sb[2] + sb[3]) * (1.f / 2048.f) + 1e-6f);
  float* xo = x1 + off;
  *(float4*)xo = *(float4*)&s[0];
  *(float4*)(xo + 4) = *(float4*)&s[4];
  const float* wr = w + c;
  float4 w0 = *(const float4*)wr, w1 = *(const float4*)(wr + 4);
  float wv[8] = {w0.x,w0.y,w0.z,w0.w,w1.x,w1.y,w1.z,w1.w};
  u16x8 r;
#pragma unroll
  for (int j = 0; j < 8; j++) r[j] = f2bf(s[j] * rn * wv[j]);
  *(u16x8*)(h2b + off) = r;
}

// ---------- bf16 GEMM body (shared by variants) ----------
__device__ __forceinline__ void gemm_body(const unsigned short* __restrict__ A,
                                          const unsigned short* __restrict__ Bt,
                                          float* __restrict__ C,
                                          int N, int K, int lda, int ldb,
                                          int m0, int n0) {
  __shared__ unsigned short As[128][32];
  __shared__ unsigned short Bs[128][32];
  const int tid = threadIdx.x;
  const int wave = tid >> 6, lane = tid & 63;
  const int wm = (wave >> 1) << 6, wn = (wave & 1) << 6;
  const int lrow = lane >> 2, lcol = lane & 3;
  const int ar0 = wave * 16 + lrow;
  const int ar1 = ar0 + 64;
  int br0 = n0 + ar0; br0 = br0 < N ? br0 : N - 1;
  int br1 = n0 + ar1; br1 = br1 < N ? br1 : N - 1;
  const unsigned short* Aptr0 = A + (size_t)(m0 + ar0) * lda + ((lcol ^ (ar0 & 3)) << 3);
  const unsigned short* Aptr1 = A + (size_t)(m0 + ar1) * lda + ((lcol ^ (ar1 & 3)) << 3);
  const unsigned short* Bptr0 = Bt + (size_t)br0 * ldb + ((lcol ^ (ar0 & 3)) << 3);
  const unsigned short* Bptr1 = Bt + (size_t)br1 * ldb + ((lcol ^ (ar1 & 3)) << 3);
  unsigned short* lA0 = &As[wave * 16][0];
  unsigned short* lA1 = &As[64 + wave * 16][0];
  unsigned short* lB0 = &Bs[wave * 16][0];
  unsigned short* lB1 = &Bs[64 + wave * 16][0];
  const int frow = lane & 15, fkb = lane >> 4;
  f32x4 acc[4][4];
#pragma unroll
  for (int i = 0; i < 4; i++)
#pragma unroll
    for (int j = 0; j < 4; j++) acc[i][j] = (f32x4){0.f, 0.f, 0.f, 0.f};

  for (int k0 = 0; k0 < K; k0 += 32) {
    gload16(Aptr0 + k0, lA0);
    gload16(Aptr1 + k0, lA1);
    gload16(Bptr0 + k0, lB0);
    gload16(Bptr1 + k0, lB1);
    __syncthreads();
    short8 af[4], bfr[4];
#pragma unroll
    for (int i = 0; i < 4; i++) {
      int ra = wm + i * 16 + frow;
      af[i] = *(const short8*)&As[ra][(fkb ^ (ra & 3)) << 3];
      int rb = wn + i * 16 + frow;
      bfr[i] = *(const short8*)&Bs[rb][(fkb ^ (rb & 3)) << 3];
    }
#pragma unroll
    for (int i = 0; i < 4; i++)
#pragma unroll
      for (int j = 0; j < 4; j++)
        acc[i][j] = __builtin_amdgcn_mfma_f32_16x16x32_bf16(af[i], bfr[j], acc[i][j], 0, 0, 0);
    __syncthreads();
  }
  const int crow = (lane >> 4) << 2, ccol = lane & 15;
#pragma unroll
  for (int i = 0; i < 4; i++) {
    const int gr = m0 + wm + i * 16 + crow;
#pragma unroll
    for (int j = 0; j < 4; j++) {
      const int gc = n0 + wn + j * 16 + ccol;
      if (gc < N) {
#pragma unroll
        for (int r = 0; r < 4; r++) C[(size_t)(gr + r) * N + gc] = acc[i][j][r];
      }
    }
  }
}

// ---------- plain GEMM ----------
__global__ void __launch_bounds__(256) gemm_bt_kernel(const unsigned short* __restrict__ A,
                                                      const unsigned short* __restrict__ Bt,
                                                      float* __restrict__ C,
                                                      int M, int N, int K, int lda, int ldb) {
  gemm_body(A, Bt, C, N, K, lda, ldb, blockIdx.x << 7, blockIdx.y << 7);
}

// ---------- merged qkv (y<48) + small (y>=48) GEMM ----------
__global__ void __launch_bounds__(256) gemm_qkv_small_kernel(const unsigned short* __restrict__ A,
                                                             const unsigned short* __restrict__ Bqkv,
                                                             const unsigned short* __restrict__ Bsmall,
                                                             float* __restrict__ Cqkv,
                                                             float* __restrict__ Csmall) {
  const int by = blockIdx.y;
  if (by < 48) gemm_body(A, Bqkv, Cqkv, 6144, 2048, 2048, 2048, blockIdx.x << 7, by << 7);
  else         gemm_body(A, Bsmall, Csmall, 272, 2048, 2048, 2048, blockIdx.x << 7, (by - 48) << 7);
}

// ---------- split-K x4 GEMM in ONE launch: blockIdx.z picks K-quarter ----------
__global__ void __launch_bounds__(256) gemm_bt_splitk4_kernel(const unsigned short* __restrict__ Abase,
                                                              const unsigned short* __restrict__ Btbase,
                                                              float* __restrict__ C0,
                                                              float* __restrict__ C1,
                                                              float* __restrict__ C2,
                                                              float* __restrict__ C3,
                                                              int M, int N, int Kq,
                                                              int lda, int ldb) {
  const unsigned short* A = Abase + (size_t)blockIdx.z * Kq;
  const unsigned short* Bt = Btbase + (size_t)blockIdx.z * Kq;
  float* C = (blockIdx.z == 0) ? C0 : (blockIdx.z == 1) ? C1 : (blockIdx.z == 2) ? C2 : C3;
  gemm_body(A, Bt, C, N, Kq, lda, ldb, blockIdx.x << 7, blockIdx.y << 7);
}

// ---------- fused MLP1: mid = bf16(silu(A*B1t^T) * (A*B2t^T)), N=8192, K=2048 ----------
__global__ void __launch_bounds__(256) gemm_dual_swiglu_kernel(const unsigned short* __restrict__ A,
                                                               const unsigned short* __restrict__ Bt,
                                                               unsigned short* __restrict__ mid) {
  __shared__ unsigned short As[128][32];
  __shared__ unsigned short B1s[128][32];
  __shared__ unsigned short B2s[128][32];
  const int tid = threadIdx.x;
  const int m0 = blockIdx.x << 7, n0 = blockIdx.y << 7;
  const int wave = tid >> 6, lane = tid & 63;
  const int wm = (wave >> 1) << 6, wn = (wave & 1) << 6;
  const int lrow = lane >> 2, lcol = lane & 3;
  const int ar0 = wave * 16 + lrow;
  const int ar1 = ar0 + 64;
  const unsigned short* Aptr0 = A + (size_t)(m0 + ar0) * 2048 + ((lcol ^ (ar0 & 3)) << 3);
  const unsigned short* Aptr1 = A + (size_t)(m0 + ar1) * 2048 + ((lcol ^ (ar1 & 3)) << 3);
  const unsigned short* B1p0 = Bt + (size_t)(n0 + ar0) * 2048 + ((lcol ^ (ar0 & 3)) << 3);
  const unsigned short* B1p1 = Bt + (size_t)(n0 + ar1) * 2048 + ((lcol ^ (ar1 & 3)) << 3);
  const unsigned short* B2p0 = B1p0 + (size_t)8192 * 2048;
  const unsigned short* B2p1 = B1p1 + (size_t)8192 * 2048;
  unsigned short* lA0 = &As[wave * 16][0];
  unsigned short* lA1 = &As[64 + wave * 16][0];
  unsigned short* lB10 = &B1s[wave * 16][0];
  unsigned short* lB11 = &B1s[64 + wave * 16][0];
  unsigned short* lB20 = &B2s[wave * 16][0];
  unsigned short* lB21 = &B2s[64 + wave * 16][0];
  const int frow = lane & 15, fkb = lane >> 4;
  f32x4 acc1[4][4], acc2[4][4];
#pragma unroll
  for (int i = 0; i < 4; i++)
#pragma unroll
    for (int j = 0; j < 4; j++) {
      acc1[i][j] = (f32x4){0.f, 0.f, 0.f, 0.f};
      acc2[i][j] = (f32x4){0.f, 0.f, 0.f, 0.f};
    }
  for (int k0 = 0; k0 < 2048; k0 += 32) {
    gload16(Aptr0 + k0, lA0);
    gload16(Aptr1 + k0, lA1);
    gload16(B1p0 + k0, lB10);
    gload16(B1p1 + k0, lB11);
    gload16(B2p0 + k0, lB20);
    gload16(B2p1 + k0, lB21);
    __syncthreads();
    short8 af[4], b1f[4], b2f[4];
#pragma unroll
    for (int i = 0; i < 4; i++) {
      int ra = wm + i * 16 + frow;
      af[i] = *(const short8*)&As[ra][(fkb ^ (ra & 3)) << 3];
      int rb = wn + i * 16 + frow;
      b1f[i] = *(const short8*)&B1s[rb][(fkb ^ (rb & 3)) << 3];
      b2f[i] = *(const short8*)&B2s[rb][(fkb ^ (rb & 3)) << 3];
    }
#pragma unroll
    for (int i = 0; i < 4; i++)
#pragma unroll
      for (int j = 0; j < 4; j++) {
        acc1[i][j] = __builtin_amdgcn_mfma_f32_16x16x32_bf16(af[i], b1f[j], acc1[i][j], 0, 0, 0);
        acc2[i][j] = __builtin_amdgcn_mfma_f32_16x16x32_bf16(af[i], b2f[j], acc2[i][j], 0, 0, 0);
      }
    __syncthreads();
  }
  const int crow = (lane >> 4) << 2, ccol = lane & 15;
#pragma unroll
  for (int i = 0; i < 4; i++) {
    const int gr = m0 + wm + i * 16 + crow;
#pragma unroll
    for (int j = 0; j < 4; j++) {
      const int gc = n0 + wn + j * 16 + ccol;
#pragma unroll
      for (int r = 0; r < 4; r++)
        mid[(size_t)(gr + r) * 8192 + gc] = f2bf(silu_f(acc1[i][j][r]) * acc2[i][j][r]);
    }
  }
}

// ---------- MERGED: causal dwconv + silu + l2norm + qk dot + gates ----------
__global__ void __launch_bounds__(256) conv_gates_kernel(const float* __restrict__ proj,
                                                         const float* __restrict__ cq,
                                                         const float* __restrict__ ck,
                                                         const float* __restrict__ cv,
                                                         const float* __restrict__ small,
                                                         const float* __restrict__ wfb,
                                                         const float* __restrict__ a_log,
                                                         const float* __restrict__ dtb,
                                                         float* __restrict__ q, float* __restrict__ k,
                                                         float* __restrict__ v,
                                                         float4* __restrict__ g4,
                                                         unsigned short* __restrict__ gab) {
  __shared__ float qksh[16];
  const int t = blockIdx.x, tid = threadIdx.x;
  const int c = tid << 3;
  float aq[8] = {0,0,0,0,0,0,0,0}, ak[8] = {0,0,0,0,0,0,0,0}, av[8] = {0,0,0,0,0,0,0,0};
#pragma unroll
  for (int i = 0; i < 4; i++) {
    const int tt = t + i - 3;
    if (tt < 0) continue;
    const float* pr = proj + (size_t)tt * 6144;
    float pq[8], pk[8], pv[8], w0[8], w1[8], w2[8];
    *(float4*)&pq[0] = *(const float4*)(pr + c);        *(float4*)&pq[4] = *(const float4*)(pr + c + 4);
    *(float4*)&pk[0] = *(const float4*)(pr + 2048 + c); *(float4*)&pk[4] = *(const float4*)(pr + 2048 + c + 4);
    *(float4*)&pv[0] = *(const float4*)(pr + 4096 + c); *(float4*)&pv[4] = *(const float4*)(pr + 4096 + c + 4);
    *(float4*)&w0[0] = *(const float4*)(cq + i * 2048 + c); *(float4*)&w0[4] = *(const float4*)(cq + i * 2048 + c + 4);
    *(float4*)&w1[0] = *(const float4*)(ck + i * 2048 + c); *(float4*)&w1[4] = *(const float4*)(ck + i * 2048 + c + 4);
    *(float4*)&w2[0] = *(const float4*)(cv + i * 2048 + c); *(float4*)&w2[4] = *(const float4*)(cv + i * 2048 + c + 4);
#pragma unroll
    for (int j = 0; j < 8; j++) { aq[j] += w0[j]*pq[j]; ak[j] += w1[j]*pk[j]; av[j] += w2[j]*pv[j]; }
  }
  float sq[8], sk[8], sv[8]; float ssq = 0.f, ssk = 0.f;
#pragma unroll
  for (int j = 0; j < 8; j++) {
    sq[j] = silu_f(aq[j]); ssq += sq[j]*sq[j];
    sk[j] = silu_f(ak[j]); ssk += sk[j]*sk[j];
    sv[j] = silu_f(av[j]);
  }
  ssq = red16(ssq); ssk = red16(ssk);
  const float rq = rsqrtf(ssq + 1e-6f) * 0.08838834764831845f;  // * DK^-0.5
  const float rk = rsqrtf(ssk + 1e-6f);
  float oq[8], ok[8]; float qkl = 0.f;
#pragma unroll
  for (int j = 0; j < 8; j++) { oq[j] = sq[j]*rq; ok[j] = sk[j]*rk; qkl += oq[j]*ok[j]; }
  qkl = red16(qkl);
  if ((tid & 15) == 0) qksh[tid >> 4] = qkl;
  float* qo = q + (size_t)t * 2048 + c;
  *(float4*)qo = *(float4*)&oq[0]; *(float4*)(qo + 4) = *(float4*)&oq[4];
  float* ko = k + (size_t)t * 2048 + c;
  *(float4*)ko = *(float4*)&ok[0]; *(float4*)(ko + 4) = *(float4*)&ok[4];
  float* vo = v + (size_t)t * 2048 + c;
  *(float4*)vo = *(float4*)&sv[0]; *(float4*)(vo + 4) = *(float4*)&sv[4];
  __syncthreads();
  if (tid < 128) {
    const float* srow = small + (size_t)t * 272;
    const int hh = tid >> 3, j = tid & 7;
    float d = 0.f;
#pragma unroll
    for (int i = 0; i < 16; i++) d += srow[j * 16 + i] * wfb[(j * 16 + i) * 16 + hh];
    d += __shfl_xor(d, 1); d += __shfl_xor(d, 2); d += __shfl_xor(d, 4);
    if (j == 0) {
      d += dtb[hh];
      float sp = (d > 20.f) ? d : log1pf(expf(d));
      float eg = expf(-expf(a_log[hh]) * sp);
      float bt = 1.f / (1.f + expf(-srow[128 + hh]));
      g4[t * 16 + hh] = make_float4(eg, bt, qksh[hh], 0.f);
    }
    gab[(size_t)t * 128 + tid] = f2bf(srow[144 + tid]);
  }
}

// ---------- scan + LATE transposes co-launched ----------
// blocks [0,512): gated delta-rule scan (known-good 8x20-reg slot version).
// blocks [512, 512+NTB): grid-stride 64x64 fp32->bf16 transpose tiles of the
// late weights (wo, wgate, wup, wdown) -- hidden in the scan's 225us shadow
// (scan occupies ~6% of the machine; transposes are pure BW work).
struct Slot { float4 k0, k1, q0, q1; float eg, qk, btv, bteg; };

__device__ __forceinline__ void load_slot(Slot& X, const float* kb, const float* qb,
                                          const float* vb, const float4* g4b, int tt) {
  const float* kp = kb + (size_t)tt * 2048;
  const float* qp = qb + (size_t)tt * 2048;
  X.k0 = *(const float4*)kp; X.k1 = *(const float4*)(kp + 4);
  X.q0 = *(const float4*)qp; X.q1 = *(const float4*)(qp + 4);
  float4 g = g4b[(size_t)tt * 16];
  float v = vb[(size_t)tt * 2048];
  X.eg = g.x; X.qk = g.z;
  X.btv = g.y * v;            // off-chain precompute
  X.bteg = g.y * g.x;
}

__device__ __forceinline__ void step_slot(const Slot& X, float (&S)[8], float* ob,
                                          bool dostore, int tt) {
  float a0 = fmaf(X.k1.x, S[4], X.k0.x * S[0]);
  float a1 = fmaf(X.k1.y, S[5], X.k0.y * S[1]);
  float a2 = fmaf(X.k1.z, S[6], X.k0.z * S[2]);
  float a3 = fmaf(X.k1.w, S[7], X.k0.w * S[3]);
  float b0 = fmaf(X.q1.x, S[4], X.q0.x * S[0]);
  float b1 = fmaf(X.q1.y, S[5], X.q0.y * S[1]);
  float b2 = fmaf(X.q1.z, S[6], X.q0.z * S[2]);
  float b3 = fmaf(X.q1.w, S[7], X.q0.w * S[3]);
  float kS = red16d((a0 + a1) + (a2 + a3));
  float qS = red16d((b0 + b1) + (b2 + b3));
  float delta = fmaf(-X.bteg, kS, X.btv);   // bt*(v - eg*kS)
  S[0] = fmaf(X.k0.x, delta, X.eg * S[0]);
  S[1] = fmaf(X.k0.y, delta, X.eg * S[1]);
  S[2] = fmaf(X.k0.z, delta, X.eg * S[2]);
  S[3] = fmaf(X.k0.w, delta, X.eg * S[3]);
  S[4] = fmaf(X.k1.x, delta, X.eg * S[4]);
  S[5] = fmaf(X.k1.y, delta, X.eg * S[5]);
  S[6] = fmaf(X.k1.z, delta, X.eg * S[6]);
  S[7] = fmaf(X.k1.w, delta, X.eg * S[7]);
  if (dostore) ob[(size_t)tt * 2048] = fmaf(X.qk, delta, X.eg * qS);
}

struct TD4 { const float* src; unsigned short* dst; int R, C, tilesX, start; };
struct TD4s { TD4 d[4]; int total; };

__global__ void __launch_bounds__(64, 1) scan_trans_kernel(const float* __restrict__ q,
                                                           const float* __restrict__ k,
                                                           const float* __restrict__ v,
                                                           const float4* __restrict__ g4,
                                                           float* __restrict__ o,
                                                           TD4s ds) {
  __shared__ float tile[64][65];   // used by transpose blocks only
  if (blockIdx.x < 512) {
    // ---- scan path (verbatim round-3 structure) ----
    const int b = blockIdx.x;            // 512 = 16 heads * 32 slices
    const int xcd = b & 7, r = b >> 3;   // XCD swizzle
    const int h = (xcd << 1) | (r >> 5);
    const int vbase = (r & 31) << 2;
    const int lane = threadIdx.x;
    const int kl = lane & 15, vl = lane >> 4;
    const int vcol = vbase + vl;
    const int koff = h * 128 + kl * 8;
    const int voff = h * 128 + vcol;
    const float* kb = k + koff;
    const float* qb = q + koff;
    const float* vb = v + voff;
    const float4* g4b = g4 + h;
    float* ob = o + voff;
    const bool dostore = (kl == 0);
    float S[8] = {0,0,0,0,0,0,0,0};
    Slot s0, s1, s2, s3, s4, s5, s6, s7;
    load_slot(s0, kb, qb, vb, g4b, 0);
    load_slot(s1, kb, qb, vb, g4b, 1);
    load_slot(s2, kb, qb, vb, g4b, 2);
    load_slot(s3, kb, qb, vb, g4b, 3);
    load_slot(s4, kb, qb, vb, g4b, 4);
    load_slot(s5, kb, qb, vb, g4b, 5);
    load_slot(s6, kb, qb, vb, g4b, 6);
    load_slot(s7, kb, qb, vb, g4b, 7);
    for (int t = 0; t < 1024; t += 8) {
      step_slot(s0, S, ob, dostore, t + 0); load_slot(s0, kb, qb, vb, g4b, t + 8);
      step_slot(s1, S, ob, dostore, t + 1); load_slot(s1, kb, qb, vb, g4b, t + 9);
      step_slot(s2, S, ob, dostore, t + 2); load_slot(s2, kb, qb, vb, g4b, t + 10);
      step_slot(s3, S, ob, dostore, t + 3); load_slot(s3, kb, qb, vb, g4b, t + 11);
      step_slot(s4, S, ob, dostore, t + 4); load_slot(s4, kb, qb, vb, g4b, t + 12);
      step_slot(s5, S, ob, dostore, t + 5); load_slot(s5, kb, qb, vb, g4b, t + 13);
      step_slot(s6, S, ob, dostore, t + 6); load_slot(s6, kb, qb, vb, g4b, t + 14);
      step_slot(s7, S, ob, dostore, t + 7); load_slot(s7, kb, qb, vb, g4b, t + 15);
    }
  } else {
    // ---- transpose path: 64 threads, 64x64 tiles, grid-stride ----
    // All late weights have R,C multiples of 64 -> no bounds checks.
    const int tid = threadIdx.x;
    const int l = tid & 15, g2 = tid >> 4;   // l: col/4, g2: row base (0..3)
    for (int tb = blockIdx.x - 512; tb < ds.total; tb += gridDim.x - 512) {
      int e = 0;
#pragma unroll
      for (int i = 1; i < 4; i++) e = (tb >= ds.d[i].start) ? i : e;
      const float* __restrict__ src = ds.d[e].src;
      unsigned short* __restrict__ dst = ds.d[e].dst;
      const int R = ds.d[e].R, C = ds.d[e].C;
      const int local = tb - ds.d[e].start;
      const int c0 = (local % ds.d[e].tilesX) * 64;
      const int r0 = (local / ds.d[e].tilesX) * 64;
#pragma unroll
      for (int ii = 0; ii < 16; ii++) {
        const int rr = g2 + 4 * ii;          // 0..63
        float4 vv = *(const float4*)(src + (size_t)(r0 + rr) * C + c0 + 4 * l);
        tile[4 * l + 0][rr] = vv.x;
        tile[4 * l + 1][rr] = vv.y;
        tile[4 * l + 2][rr] = vv.z;
        tile[4 * l + 3][rr] = vv.w;
      }
      __syncthreads();
#pragma unroll
      for (int ii = 0; ii < 16; ii++) {
        const int cc = g2 + 4 * ii;          // 0..63
        u16x4 oo;
        oo[0] = f2bf(tile[cc][4 * l + 0]);
        oo[1] = f2bf(tile[cc][4 * l + 1]);
        oo[2] = f2bf(tile[cc][4 * l + 2]);
        oo[3] = f2bf(tile[cc][4 * l + 3]);
        *(u16x4*)(dst + (size_t)(c0 + cc) * R + r0 + 4 * l) = oo;
      }
      __syncthreads();
    }
  }
}

// ---------- o_gated = bf16(rmsnorm_head(o)*w * silu(gate)) ----------
__global__ void __launch_bounds__(256) gate_o_kernel(const float* __restrict__ o,
                                                     const float* __restrict__ gate,
                                                     const float* __restrict__ onw,
                                                     unsigned short* __restrict__ ogb) {
  const int t = blockIdx.x, tid = threadIdx.x;
  const int c = tid << 3;
  const float* orow = o + (size_t)t * 2048 + c;
  float ov[8]; *(float4*)&ov[0] = *(const float4*)orow; *(float4*)&ov[4] = *(const float4*)(orow + 4);
  float ss = 0.f;
#pragma unroll
  for (int j = 0; j < 8; j++) ss += ov[j] * ov[j];
  ss = red16(ss);
  const float rn = rsqrtf(ss * (1.f / 128.f) + 1e-6f);
  const int dv = (tid & 15) << 3;
  float wv[8]; *(float4*)&wv[0] = *(const float4*)(onw + dv); *(float4*)&wv[4] = *(const float4*)(onw + dv + 4);
  const float* grow = gate + (size_t)t * 2048 + c;
  float gv[8]; *(float4*)&gv[0] = *(const float4*)grow; *(float4*)&gv[4] = *(const float4*)(grow + 4);
  u16x8 r;
#pragma unroll
  for (int j = 0; j < 8; j++) r[j] = f2bf(ov[j] * rn * wv[j] * silu_f(gv[j]));
  *(u16x8*)(ogb + (size_t)t * 2048 + c) = r;
}

// ---------- out = a + p0+p1+p2+p3 ----------
__global__ void final_add5_kernel(const float* __restrict__ a, const float* __restrict__ p0,
                                  const float* __restrict__ p1, const float* __restrict__ p2,
                                  const float* __restrict__ p3, float* __restrict__ out) {
  const int NU = 1024 * 512;
  for (int u = blockIdx.x * blockDim.x + threadIdx.x; u < NU; u += gridDim.x * blockDim.x) {
    float4 va = ((const float4*)a)[u];
    float4 v0 = ((const float4*)p0)[u];
    float4 v1 = ((const float4*)p1)[u];
    float4 v2 = ((const float4*)p2)[u];
    float4 v3 = ((const float4*)p3)[u];
    va.x += v0.x + v1.x + v2.x + v3.x;
    va.y += v0.y + v1.y + v2.y + v3.y;
    va.z += v0.z + v1.z + v2.z + v3.z;
    va.w += v0.w + v1.w + v2.w + v3.w;
    ((float4*)out)[u] = va;
  }
}

// ---------- ws layout (bytes) ----------
constexpr size_t SZ_WQKVT   = (size_t)6144 * 2048 * 2;
constexpr size_t SZ_WSMALLT = (size_t)272 * 2048 * 2;
constexpr size_t SZ_WGBT    = (size_t)2048 * 128 * 2;
constexpr size_t SZ_WOT     = (size_t)2048 * 2048 * 2;
constexpr size_t SZ_WMLP1T  = (size_t)16384 * 2048 * 2;
constexpr size_t SZ_WDOWNT  = (size_t)2048 * 8192 * 2;
constexpr size_t OFF_WQKVT   = 0;
constexpr size_t OFF_WSMALLT = OFF_WQKVT + SZ_WQKVT;
constexpr size_t OFF_WGBT    = OFF_WSMALLT + SZ_WSMALLT;
constexpr size_t OFF_WOT     = OFF_WGBT + SZ_WGBT;
constexpr size_t OFF_WMLP1T  = OFF_WOT + SZ_WOT;
constexpr size_t OFF_WDOWNT  = OFF_WMLP1T + SZ_WMLP1T;
constexpr size_t A0          = OFF_WDOWNT + SZ_WDOWNT;
constexpr size_t OFF_HB    = A0;
constexpr size_t OFF_PROJ  = OFF_HB + (size_t)1024 * 2048 * 2;
constexpr size_t OFF_SMALL = OFF_PROJ + (size_t)1024 * 6144 * 4;
constexpr size_t OFF_Q     = OFF_SMALL + (size_t)1024 * 272 * 4;
constexpr size_t OFF_K     = OFF_Q + (size_t)1024 * 2048 * 4;
constexpr size_t OFF_V     = OFF_K + (size_t)1024 * 2048 * 4;
constexpr size_t OFF_G     = OFF_V + (size_t)1024 * 2048 * 4;   // scan over-read pad
constexpr size_t OFF_BETA  = OFF_G + (size_t)1024 * 16 * 4;
constexpr size_t OFF_GAB   = OFF_BETA + (size_t)1024 * 16 * 4;
constexpr size_t OFF_GATE  = OFF_GAB + (size_t)1024 * 128 * 2;
constexpr size_t OFF_O     = OFF_GATE + (size_t)1024 * 2048 * 4;
constexpr size_t OFF_OGB   = OFF_O + (size_t)1024 * 2048 * 4;
constexpr size_t OFF_OPROJ = OFF_OGB + (size_t)1024 * 2048 * 2;
constexpr size_t OFF_X1    = OFF_OPROJ + (size_t)1024 * 2048 * 4;
constexpr size_t OFF_H2B   = OFF_X1 + (size_t)1024 * 2048 * 4;
constexpr size_t OFF_MID    = A0 + (size_t)1024 * 16384 * 4;   // overlaps dead GATE/O/OGB/OPROJ only
constexpr size_t OFF_MLPOUT = OFF_H2B + (size_t)1024 * 2048 * 2;
constexpr size_t OFF_QKB    = OFF_MLPOUT + (size_t)1024 * 2048 * 4;   // (layout keep)
constexpr size_t OFF_G4     = OFF_QKB + (size_t)1024 * 16 * 4;        // [1040][16] float4 (tail pad)
constexpr size_t OFF_MLPOUT2= OFF_G4 + (size_t)1040 * 16 * 16;
constexpr size_t WS_NEED    = OFF_MLPOUT2 + (size_t)1024 * 2048 * 4;
// liveness aliases for split-K partials:
constexpr size_t OFF_OPROJ2 = OFF_O;                                  // dead `of` after gate_o
constexpr size_t OFF_OPROJ3 = OFF_PROJ;                               // dead projf after conv_gates
constexpr size_t OFF_OPROJ4 = OFF_PROJ + (size_t)1024 * 2048 * 4;
constexpr size_t OFF_MLPOUT3 = OFF_Q;                                 // dead qf after scan
constexpr size_t OFF_MLPOUT4 = OFF_K;                                 // dead kf after scan

extern "C" void kernel_launch(void* const* d_in, const int* in_sizes, int n_in,
                              void* d_out, int out_size, void* d_ws, size_t ws_size,
                              hipStream_t stream) {
  (void)in_sizes; (void)n_in; (void)out_size;
  const float* x     = (const float*)d_in[0];
  const float* wq    = (const float*)d_in[1];
  const float* wk    = (const float*)d_in[2];
  const float* wv    = (const float*)d_in[3];
  const float* cq    = (const float*)d_in[4];
  const float* ck    = (const float*)d_in[5];
  const float* cv    = (const float*)d_in[6];
  const float* wfa   = (const float*)d_in[7];
  const float* wfb   = (const float*)d_in[8];
  const float* wb    = (const float*)d_in[9];
  const float* wga   = (const float*)d_in[10];
  const float* wgb   = (const float*)d_in[11];
  const float* a_log = (const float*)d_in[12];
  const float* dtb   = (const float*)d_in[13];
  const float* onw   = (const float*)d_in[14];
  const float* wo    = (const float*)d_in[15];
  const float* ln1   = (const float*)d_in[16];
  const float* ln2   = (const float*)d_in[17];
  const float* wgate = (const float*)d_in[18];
  const float* wup   = (const float*)d_in[19];
  const float* wdown = (const float*)d_in[20];
  float* out = (float*)d_out;
  char* ws = (char*)d_ws;
  if (ws_size < WS_NEED) return;

  unsigned short* wqkvT   = (unsigned short*)(ws + OFF_WQKVT);
  unsigned short* wsmallT = (unsigned short*)(ws + OFF_WSMALLT);
  unsigned short* wgbT    = (unsigned short*)(ws + OFF_WGBT);
  unsigned short* woT     = (unsigned short*)(ws + OFF_WOT);
  unsigned short* wmlp1T  = (unsigned short*)(ws + OFF_WMLP1T);
  unsigned short* wdownT  = (unsigned short*)(ws + OFF_WDOWNT);
  unsigned short* hb      = (unsigned short*)(ws + OFF_HB);
  float* projf  = (float*)(ws + OFF_PROJ);
  float* smallf = (float*)(ws + OFF_SMALL);
  float* qf     = (float*)(ws + OFF_Q);
  float* kf     = (float*)(ws + OFF_K);
  float* vf     = (float*)(ws + OFF_V);
  unsigned short* gab = (unsigned short*)(ws + OFF_GAB);
  float* gatef  = (float*)(ws + OFF_GATE);
  float* of     = (float*)(ws + OFF_O);
  unsigned short* ogb = (unsigned short*)(ws + OFF_OGB);
  float* oprojf = (float*)(ws + OFF_OPROJ);
  float* oproj2f= (float*)(ws + OFF_OPROJ2);
  float* oproj3f= (float*)(ws + OFF_OPROJ3);
  float* oproj4f= (float*)(ws + OFF_OPROJ4);
  float* x1f    = (float*)(ws + OFF_X1);
  unsigned short* h2b = (unsigned short*)(ws + OFF_H2B);
  unsigned short* midb = (unsigned short*)(ws + OFF_MID);
  float* mlpoutf  = (float*)(ws + OFF_MLPOUT);
  float* mlpout2f = (float*)(ws + OFF_MLPOUT2);
  float* mlpout3f = (float*)(ws + OFF_MLPOUT3);
  float* mlpout4f = (float*)(ws + OFF_MLPOUT4);
  float4* g4    = (float4*)(ws + OFF_G4);

  // --- early transposes (needed before qkv/small/gatef GEMMs) ---
  TDescs tds;
  int st = 0;
  auto set = [&](int i, const float* s, unsigned short* d, int R, int C) {
    int tx = (C + 63) / 64, ty = (R + 63) / 64;
    tds.d[i] = TDesc{s, d, R, C, tx, st};
    st += tx * ty;
  };
  set(0, wq, wqkvT, 2048, 2048);
  set(1, wk, wqkvT + (size_t)2048 * 2048, 2048, 2048);
  set(2, wv, wqkvT + (size_t)4096 * 2048, 2048, 2048);
  set(3, wfa, wsmallT, 2048, 128);
  set(4, wb, wsmallT + (size_t)128 * 2048, 2048, 16);
  set(5, wga, wsmallT + (size_t)144 * 2048, 2048, 128);
  set(6, wgb, wgbT, 128, 2048);
  trans_early_kernel<<<st, 256, 0, stream>>>(tds);

  // --- late transposes ride inside the scan launch ---
  TD4s lds4;
  int lt = 0;
  auto set4 = [&](int i, const float* s, unsigned short* d, int R, int C) {
    int tx = C / 64, ty = R / 64;
    lds4.d[i] = TD4{s, d, R, C, tx, lt};
    lt += tx * ty;
  };
  set4(0, wo, woT, 2048, 2048);
  set4(1, wgate, wmlp1T, 2048, 8192);
  set4(2, wup, wmlp1T + (size_t)8192 * 2048, 2048, 8192);
  set4(3, wdown, wdownT, 8192, 2048);
  lds4.total = lt;

  rmsnorm_bf16_kernel<<<1024, 256, 0, stream>>>(x, ln1, hb);
  gemm_qkv_small_kernel<<<dim3(8, 51), 256, 0, stream>>>(hb, wqkvT, wsmallT, projf, smallf);
  conv_gates_kernel<<<1024, 256, 0, stream>>>(projf, cq, ck, cv, smallf, wfb, a_log, dtb,
                                              qf, kf, vf, g4, gab);
  gemm_bt_kernel<<<dim3(8, 16), 256, 0, stream>>>(gab, wgbT, gatef, 1024, 2048, 128, 128, 128);
  scan_trans_kernel<<<512 + 2048, 64, 0, stream>>>(qf, kf, vf, g4, of, lds4);
  gate_o_kernel<<<1024, 256, 0, stream>>>(of, gatef, onw, ogb);
  gemm_bt_splitk4_kernel<<<dim3(8, 16, 4), 256, 0, stream>>>(ogb, woT,
      oprojf, oproj2f, oproj3f, oproj4f, 1024, 2048, 512, 2048, 2048);
  add5_rmsnorm_kernel<<<1024, 256, 0, stream>>>(x, oprojf, oproj2f, oproj3f, oproj4f,
                                                ln2, x1f, h2b);
  gemm_dual_swiglu_kernel<<<dim3(8, 64), 256, 0, stream>>>(h2b, wmlp1T, midb);
  gemm_bt_splitk4_kernel<<<dim3(8, 16, 4), 256, 0, stream>>>(midb, wdownT,
      mlpoutf, mlpout2f, mlpout3f, mlpout4f, 1024, 2048, 2048, 8192, 8192);
  final_add5_kernel<<<2048, 256, 0, stream>>>(x1f, mlpoutf, mlpout2f, mlpout3f, mlpout4f, out);
}